// Round 12
// baseline (400.794 us; speedup 1.0000x reference)
//
#include <hip/hip_runtime.h>

#define DIM 768
#define HEADS 12
#define HD 64
#define NB 128
#define ROWS_ALL 25216   // 197*128
#define ROWS_KV  25088   // 196*128
#define NCHUNK 64        // chunks per head; chunk c covers key-tiles [49c/8, 49(c+1)/8)

typedef __attribute__((ext_vector_type(8))) short short8;
typedef __attribute__((ext_vector_type(4))) short short4v;
typedef __attribute__((ext_vector_type(4))) float f32x4;
typedef __attribute__((ext_vector_type(4))) unsigned int uint4v;

__device__ __forceinline__ unsigned short f2bf(float f) {
  union { float f; unsigned u; } a; a.f = f;
  return (unsigned short)((a.u + 0x7fffu + ((a.u >> 16) & 1u)) >> 16);
}
__device__ __forceinline__ float bf2f(unsigned short u) {
  union { unsigned u; float f; } a; a.u = ((unsigned)u) << 16;
  return a.f;
}

__device__ __forceinline__ void gload16(const void* g, void* l) {
  __builtin_amdgcn_global_load_lds(
      (__attribute__((address_space(1))) void*)g,
      (__attribute__((address_space(3))) void*)l, 16, 0, 0);
}

// ------ fused: LN1 over concat([cls,x]) -> bf16 xx + f32 q0; cast 5 W ---
__global__ __launch_bounds__(256) void ln1_cast(
    const float* __restrict__ x, const float* __restrict__ cls,
    const float* __restrict__ g, const float* __restrict__ b,
    unsigned short* __restrict__ xx, float* __restrict__ q0f,
    const float* __restrict__ Wq, const float* __restrict__ Wk,
    const float* __restrict__ Wv, const float* __restrict__ fcw,
    const float* __restrict__ pw, unsigned short* __restrict__ wpk)
{
  int blk = blockIdx.x, tid = threadIdx.x;
  if (blk < ROWS_ALL / 4) {
    int row = blk * 4 + (tid >> 6);
    int lane = tid & 63;
    const float* src = (row < NB) ? (cls + (size_t)row * DIM)
                                  : (x + (size_t)(row - NB) * DIM);
    float4 v[3];
    float s = 0.f;
#pragma unroll
    for (int i = 0; i < 3; ++i) {
      v[i] = ((const float4*)src)[lane + 64 * i];
      s += v[i].x + v[i].y + v[i].z + v[i].w;
    }
#pragma unroll
    for (int o = 32; o; o >>= 1) s += __shfl_xor(s, o);
    float mean = s * (1.f / 768.f);
    float ss = 0.f;
#pragma unroll
    for (int i = 0; i < 3; ++i) {
      float a0 = v[i].x - mean, a1 = v[i].y - mean, a2 = v[i].z - mean, a3 = v[i].w - mean;
      ss += a0 * a0 + a1 * a1 + a2 * a2 + a3 * a3;
    }
#pragma unroll
    for (int o = 32; o; o >>= 1) ss += __shfl_xor(ss, o);
    float rs = rsqrtf(ss * (1.f / 768.f) + 1e-5f);
#pragma unroll
    for (int i = 0; i < 3; ++i) {
      int c4 = lane + 64 * i;
      float4 gv = ((const float4*)g)[c4];
      float4 bv = ((const float4*)b)[c4];
      float o0 = (v[i].x - mean) * rs * gv.x + bv.x;
      float o1 = (v[i].y - mean) * rs * gv.y + bv.y;
      float o2 = (v[i].z - mean) * rs * gv.z + bv.z;
      float o3 = (v[i].w - mean) * rs * gv.w + bv.w;
      ushort4 u; u.x = f2bf(o0); u.y = f2bf(o1); u.z = f2bf(o2); u.w = f2bf(o3);
      ((ushort4*)(xx + (size_t)row * DIM))[c4] = u;
      if (row < NB) {
        float4 fo; fo.x = o0; fo.y = o1; fo.z = o2; fo.w = o3;
        ((float4*)(q0f + (size_t)row * DIM))[c4] = fo;
      }
    }
  } else {
    int idx = blk - ROWS_ALL / 4;          // [0, 2880)
    int w = idx / 576;                     // matrix id, uniform per block
    int j4 = (idx % 576) * 256 + tid;      // float4 index within matrix
    const float* s = (w == 0) ? Wq : (w == 1) ? Wk : (w == 2) ? Wv
                   : (w == 3) ? fcw : pw;
    float4 v = ((const float4*)s)[j4];
    ushort4 u; u.x = f2bf(v.x); u.y = f2bf(v.y); u.z = f2bf(v.z); u.w = f2bf(v.w);
    ((ushort4*)(wpk + (size_t)w * (DIM * DIM)))[j4] = u;
  }
}

// ======= fused QKV GEMMs: big operand via LDS, WEIGHT direct to regs ====
// 128x128 tile, BK=32. Only the large operand (xx panel) is staged in LDS
// (8KB dbuf, 1-barrier scheme, stage issued 1 step ahead). The L2-resident
// weight operand streams global->register with a 1-step reg double-buffer.
// vmcnt(0) per step (counted waits unsafe: compiler weight-loads share the
// counter). Regs: 64 AGPR + ~90 VGPR -> (256,3); NEVER force 4+ waves/EU
// here (round-6: forcing 8 spilled, 87us -> 989us).
__global__ __launch_bounds__(256, 3) void gemm_fused(
    const unsigned short* __restrict__ xxkv, const unsigned short* __restrict__ Wkb,
    unsigned short* __restrict__ Kbf,
    const unsigned short* __restrict__ Wvb, unsigned short* __restrict__ Vtb,
    const unsigned short* __restrict__ xxall, const unsigned short* __restrict__ Wqb,
    unsigned short* __restrict__ Qbf)
{
  __shared__ unsigned short Lsm[2][128 * 32];   // big operand, 8KB x2
  int tid = threadIdx.x, wid = tid >> 6, lane = tid & 63;
  int l15 = lane & 15, l4 = lane >> 4;

  int nwg = gridDim.x;
  int bid = blockIdx.x;
  int q8 = nwg >> 3, r8 = nwg & 7;
  int xcd = bid & 7, rank = bid >> 3;
  int swz = (xcd < r8 ? xcd * (q8 + 1) : r8 * (q8 + 1) + (xcd - r8) * q8) + rank;

  const unsigned short *BIG, *WGT;
  unsigned short* C;
  int N, row0, col0;
  bool bigIsA;
  const int K = DIM;
  if (swz < 1176) {                 // K = xx_kv @ Wk^T : big=A, wgt=B
    BIG = xxkv; WGT = Wkb; C = Kbf; N = DIM; bigIsA = true;
    row0 = (swz / 6) * 128; col0 = (swz % 6) * 128;
  } else if (swz < 2352) {          // V^T = Wv @ xx_kv^T : big=Bt, wgt=A
    int inner = swz - 1176;
    BIG = xxkv; WGT = Wvb; C = Vtb; N = ROWS_KV; bigIsA = false;
    row0 = (inner % 6) * 128; col0 = (inner / 6) * 128;
  } else {                          // Q = xx_cls @ Wq^T (pre-scaled)
    int inner = swz - 2352;
    BIG = xxall; WGT = Wqb; C = Qbf; N = DIM; bigIsA = true;
    row0 = 0; col0 = inner * 128;
  }
  float csc = (swz >= 2352) ? 0.18033688011112042f : 1.0f;  // log2e/8 for Q

  // LDS staging of BIG rows (conflict-free swizzle q = l4 ^ ((row>>1)&3))
  int brow0 = bigIsA ? row0 : col0;
  int srow = tid >> 2;
  int sb = (tid & 3) ^ ((srow >> 1) & 3);
  const char* Gg = (const char*)BIG + (size_t)(brow0 + srow) * K * 2 + sb * 16;
  const size_t rstep = (size_t)64 * K * 2;

  // weight fragment row pointers (4 fragments x 16 rows, this lane's row)
  int wbase = bigIsA ? col0 : row0;
  int wsub = bigIsA ? (wid & 1) * 64 : (wid >> 1) * 64;
  const char* wrow[4];
#pragma unroll
  for (int f = 0; f < 4; ++f)
    wrow[f] = (const char*)(WGT + (size_t)(wbase + wsub + f * 16 + l15) * K) + l4 * 16;

#define STG(s, kt) do {                                               \
    char* la = (char*)Lsm[s] + wid * 1024;                            \
    gload16(Gg + (size_t)(kt) * 64,         la);                      \
    gload16(Gg + (size_t)(kt) * 64 + rstep, la + 4096);               \
  } while (0)
#define WLOAD(dst, kt) do {                                           \
    _Pragma("unroll")                                                 \
    for (int f = 0; f < 4; ++f)                                       \
      dst[f] = *(const short8*)(wrow[f] + (size_t)(kt) * 64);         \
  } while (0)

  f32x4 acc[4][4] = {};
  int wr = (wid >> 1) * 64, wc = (wid & 1) * 64;
  int lbase = bigIsA ? wr : wc;    // LDS fragment base rows
  short8 w0[4], w1[4], fr[4];
  const int nk = K >> 5;            // 24 K-steps of BK=32

#define KSTEP(CUR, WCUR, WNXT, T) do {                                \
    asm volatile("s_waitcnt vmcnt(0)" ::: "memory");                  \
    __builtin_amdgcn_s_barrier();                                     \
    asm volatile("" ::: "memory");                                    \
    if ((T) + 1 < nk) { STG((CUR) ^ 1, (T) + 1); WLOAD(WNXT, (T) + 1); } \
    asm volatile("" ::: "memory");                                    \
    const char* Lb = (const char*)Lsm[CUR];                           \
    _Pragma("unroll")                                                 \
    for (int j = 0; j < 4; ++j) {                                     \
      int row = lbase + j * 16 + l15;                                 \
      fr[j] = *(const short8*)(Lb + row * 64 + ((l4 ^ ((row >> 1) & 3)) << 4)); \
    }                                                                 \
    __builtin_amdgcn_s_setprio(1);                                    \
    if (bigIsA) {                                                     \
      _Pragma("unroll")                                               \
      for (int m = 0; m < 4; ++m)                                     \
        _Pragma("unroll")                                             \
        for (int n = 0; n < 4; ++n)                                   \
          acc[m][n] = __builtin_amdgcn_mfma_f32_16x16x32_bf16(        \
              fr[m], WCUR[n], acc[m][n], 0, 0, 0);                    \
    } else {                                                          \
      _Pragma("unroll")                                               \
      for (int m = 0; m < 4; ++m)                                     \
        _Pragma("unroll")                                             \
        for (int n = 0; n < 4; ++n)                                   \
          acc[m][n] = __builtin_amdgcn_mfma_f32_16x16x32_bf16(        \
              WCUR[m], fr[n], acc[m][n], 0, 0, 0);                    \
    }                                                                 \
    __builtin_amdgcn_s_setprio(0);                                    \
    asm volatile("" ::: "memory");                                    \
  } while (0)

  WLOAD(w0, 0);
  STG(0, 0);
  for (int t = 0; t < nk; t += 2) {
    KSTEP(0, w0, w1, t);
    KSTEP(1, w1, w0, t + 1);
  }
#undef KSTEP
#undef WLOAD
#undef STG

#pragma unroll
  for (int m = 0; m < 4; ++m)
#pragma unroll
    for (int n = 0; n < 4; ++n)
#pragma unroll
      for (int r = 0; r < 4; ++r) {
        int rr = row0 + wr + m * 16 + l4 * 4 + r;
        int cc = col0 + wc + n * 16 + l15;
        C[(size_t)rr * N + cc] = f2bf(acc[m][n][r] * csc);
      }
}

// ======= 128x128 tile GEMM (small M epilogue cases), BK=64, 1 barrier ===
// EPI 1: +bias, silu(1.702), bf16 store; 2: +bias +addsrc, f32 store
template <int EPI>
__global__ __launch_bounds__(256, 2) void gemm_bt64(
    const unsigned short* __restrict__ A, const unsigned short* __restrict__ Bt,
    void* __restrict__ Cout, int M, int N, int K,
    const float* __restrict__ bias, const float* __restrict__ addsrc)
{
  __shared__ unsigned short Asm[2][128 * 64];
  __shared__ unsigned short Bsm[2][128 * 64];
  int tid = threadIdx.x, wid = tid >> 6, lane = tid & 63;
  int l15 = lane & 15, l4 = lane >> 4;
  int row0 = blockIdx.y * 128, col0 = blockIdx.x * 128;

  int srow = tid >> 3;
  int scol = ((tid & 7) ^ (srow & 7)) << 4;
  const char* Ag = (const char*)A + (size_t)(row0 + srow) * K * 2 + scol;
  const char* Bg = (const char*)Bt + (size_t)(col0 + srow) * K * 2 + scol;
  size_t rstep32 = (size_t)32 * K * 2;

#define STAGE(buf, kt) do {                                           \
    const char* a0 = Ag + (size_t)(kt) * 128;                         \
    const char* b0 = Bg + (size_t)(kt) * 128;                         \
    char* la = (char*)Asm[buf] + wid * 1024;                          \
    char* lb = (char*)Bsm[buf] + wid * 1024;                          \
    gload16(a0,                la);                                   \
    gload16(a0 + rstep32,      la + 4096);                            \
    gload16(a0 + 2 * rstep32,  la + 8192);                            \
    gload16(a0 + 3 * rstep32,  la + 12288);                           \
    gload16(b0,                lb);                                   \
    gload16(b0 + rstep32,      lb + 4096);                            \
    gload16(b0 + 2 * rstep32,  lb + 8192);                            \
    gload16(b0 + 3 * rstep32,  lb + 12288);                           \
  } while (0)

  f32x4 acc[4][4] = {};
  int wr = (wid >> 1) * 64, wc = (wid & 1) * 64;
  int nk = K >> 6;                 // BK=64
  STAGE(0, 0);
  for (int t = 0; t < nk; ++t) {
    int cur = t & 1;
    __builtin_amdgcn_s_barrier();
    asm volatile("" ::: "memory");
    if (t + 1 < nk) {
      STAGE(cur ^ 1, t + 1);
      asm volatile("s_waitcnt vmcnt(8)" ::: "memory");
    } else {
      asm volatile("s_waitcnt vmcnt(0)" ::: "memory");
    }
    const char* Ab = (const char*)Asm[cur];
    const char* Bb = (const char*)Bsm[cur];
#pragma unroll
    for (int kk = 0; kk < 2; ++kk) {
      short8 aF[4], bF[4];
#pragma unroll
      for (int m = 0; m < 4; ++m) {
        int row = wr + m * 16 + l15;
        aF[m] = *(const short8*)(Ab + row * 128 + ((((kk << 2) | l4) ^ (row & 7)) << 4));
      }
#pragma unroll
      for (int n = 0; n < 4; ++n) {
        int row = wc + n * 16 + l15;
        bF[n] = *(const short8*)(Bb + row * 128 + ((((kk << 2) | l4) ^ (row & 7)) << 4));
      }
#pragma unroll
      for (int m = 0; m < 4; ++m)
#pragma unroll
        for (int n = 0; n < 4; ++n)
          acc[m][n] = __builtin_amdgcn_mfma_f32_16x16x32_bf16(aF[m], bF[n], acc[m][n], 0, 0, 0);
    }
    asm volatile("" ::: "memory");
  }
#undef STAGE
#pragma unroll
  for (int m = 0; m < 4; ++m)
#pragma unroll
    for (int n = 0; n < 4; ++n)
#pragma unroll
      for (int r = 0; r < 4; ++r) {
        int rr = row0 + wr + m * 16 + l4 * 4 + r;
        int cc = col0 + wc + n * 16 + l15;
        float v = acc[m][n][r];
        if (EPI == 1) {
          v += bias[cc];
          v = v / (1.f + __expf(-1.702f * v));
          ((unsigned short*)Cout)[(size_t)rr * N + cc] = f2bf(v);
        } else {
          v += bias[cc] + addsrc[(size_t)rr * N + cc];
          ((float*)Cout)[(size_t)rr * N + cc] = v;
        }
      }
}

// ---------------- flash-decode attention partials (swapped QK^T) --------
// Static-max softmax; Q pre-scaled by log2e/8 in gemm_fused, so
// p = exp2(S_scaled) directly — no per-score multiply.
__global__ __launch_bounds__(256, 4) void attn_partial(
    const unsigned short* __restrict__ Qb, const unsigned short* __restrict__ Kb,
    const unsigned short* __restrict__ Vt,
    unsigned short* __restrict__ Op, float* __restrict__ lp)
{
  __shared__ unsigned short Klds[2][64 * 64];
  __shared__ unsigned short Vlds[2][64 * 64];
  int tid = threadIdx.x, wid = tid >> 6, lane = tid & 63;
  int l15 = lane & 15, l4 = lane >> 4;
  int head = blockIdx.x >> 6, chunk = blockIdx.x & 63;
  int t0 = (49 * chunk) >> 3;
  int nkt = ((49 * (chunk + 1)) >> 3) - t0;   // 6 or 7

  short8 bQ[2][2];
#pragma unroll
  for (int m = 0; m < 2; ++m)
#pragma unroll
    for (int kk = 0; kk < 2; ++kk) {
      int qrow = wid * 32 + m * 16 + l15;
      bQ[m][kk] = *(const short8*)(Qb + (size_t)qrow * DIM + head * HD + kk * 32 + l4 * 8);
    }
  f32x4 accO[2][4] = {};
  float lrun[2] = { 0.f, 0.f };

  int srow = tid >> 3;                       // 0..31 within a 32-row pass
  int sblk = (tid & 7) ^ (srow & 7);
  const char* Kg = (const char*)(Kb + (size_t)(t0 * 64 + srow) * DIM + head * HD) + sblk * 16;
  const char* Vg = (const char*)(Vt + (size_t)(head * HD + srow) * ROWS_KV + t0 * 64) + sblk * 16;

#define STAGEKV(buf, kt) do {                                         \
    const char* k0 = Kg + (size_t)(kt) * 64 * DIM * 2;                \
    const char* v0 = Vg + (size_t)(kt) * 128;                         \
    char* lk = (char*)Klds[buf] + wid * 1024;                         \
    char* lv = (char*)Vlds[buf] + wid * 1024;                         \
    gload16(k0,                        lk);                           \
    gload16(k0 + (size_t)32 * DIM * 2, lk + 4096);                    \
    gload16(v0,                        lv);                           \
    gload16(v0 + (size_t)32 * ROWS_KV * 2, lv + 4096);                \
  } while (0)

  STAGEKV(0, 0);
  for (int kt = 0; kt < nkt; ++kt) {
    int cur = kt & 1;
    __builtin_amdgcn_s_barrier();   // all waves done reading buf[cur^1]
    asm volatile("" ::: "memory");
    if (kt + 1 < nkt) {
      STAGEKV(cur ^ 1, kt + 1);
      asm volatile("s_waitcnt vmcnt(4)" ::: "memory");
    } else {
      asm volatile("s_waitcnt vmcnt(0)" ::: "memory");
    }

    // S^T[key][q]: sc[n][m][r] = Ssc[q0+m*16+l15][key = n*16 + l4*4 + r]
    f32x4 sc[4][2] = {};
    __builtin_amdgcn_s_setprio(1);
#pragma unroll
    for (int kk = 0; kk < 2; ++kk) {
      short8 aK[4];
#pragma unroll
      for (int n = 0; n < 4; ++n) {
        int krow = n * 16 + l15;
        int blk = ((kk << 2) | l4) ^ (krow & 7);
        aK[n] = *(const short8*)((const char*)Klds[cur] + krow * 128 + blk * 16);
      }
#pragma unroll
      for (int n = 0; n < 4; ++n)
#pragma unroll
        for (int m = 0; m < 2; ++m)
          sc[n][m] = __builtin_amdgcn_mfma_f32_16x16x32_bf16(aK[n], bQ[m][kk], sc[n][m], 0, 0, 0);
    }
    __builtin_amdgcn_s_setprio(0);

    // static-max softmax: p = 2^(S_scaled); sum; pack bf16 via cvt_pk
    short8 pB[2][2];
#pragma unroll
    for (int m = 0; m < 2; ++m) {
      float rsum = 0.f;
#pragma unroll
      for (int n = 0; n < 4; ++n)
#pragma unroll
        for (int r = 0; r < 4; ++r) {
          float p;
          asm("v_exp_f32 %0, %1" : "=v"(p) : "v"(sc[n][m][r]));
          sc[n][m][r] = p;
          rsum += p;
        }
      rsum += __shfl_xor(rsum, 16);
      rsum += __shfl_xor(rsum, 32);
      lrun[m] += rsum;
#pragma unroll
      for (int kk2 = 0; kk2 < 2; ++kk2) {
        uint4v pw;
#pragma unroll
        for (int w = 0; w < 4; ++w) {
          int n = 2 * kk2 + (w >> 1);
          int r0 = (w & 1) * 2;
          unsigned int u;
          asm("v_cvt_pk_bf16_f32 %0, %1, %2"
              : "=v"(u) : "v"(sc[n][m][r0]), "v"(sc[n][m][r0 + 1]));
          pw[w] = u;
        }
        pB[m][kk2] = __builtin_bit_cast(short8, pw);
      }
    }

    // O^T += V'^T P'
    __builtin_amdgcn_s_setprio(1);
#pragma unroll
    for (int kk2 = 0; kk2 < 2; ++kk2) {
      short8 aV[4];
#pragma unroll
      for (int nb = 0; nb < 4; ++nb) {
        int row = nb * 16 + l15;
        int blk1 = (kk2 << 2) | (l4 >> 1);
        int in1 = (l4 & 1) << 3;
        const char* vb = (const char*)Vlds[cur] + row * 128;
        short4v lo = *(const short4v*)(vb + (((blk1 ^ (row & 7)) << 4) | in1));
        short4v hi = *(const short4v*)(vb + ((((blk1 + 2) ^ (row & 7)) << 4) | in1));
        aV[nb] = __builtin_shufflevector(lo, hi, 0, 1, 2, 3, 4, 5, 6, 7);
      }
#pragma unroll
      for (int m = 0; m < 2; ++m)
#pragma unroll
        for (int nb = 0; nb < 4; ++nb)
          accO[m][nb] = __builtin_amdgcn_mfma_f32_16x16x32_bf16(aV[nb], pB[m][kk2], accO[m][nb], 0, 0, 0);
    }
    __builtin_amdgcn_s_setprio(0);
    asm volatile("" ::: "memory");
  }
#undef STAGEKV
  size_t pb = (size_t)(head * NCHUNK + chunk) * 128;
#pragma unroll
  for (int m = 0; m < 2; ++m) {
    int q = wid * 32 + m * 16 + l15;
#pragma unroll
    for (int nb = 0; nb < 4; ++nb) {
      ushort4 o;
      o.x = f2bf(accO[m][nb][0]); o.y = f2bf(accO[m][nb][1]);
      o.z = f2bf(accO[m][nb][2]); o.w = f2bf(accO[m][nb][3]);
      *(ushort4*)(Op + (pb + q) * 64 + nb * 16 + l4 * 4) = o;
    }
    if (l4 == 0) {
      lp[pb + q] = lrun[m];
    }
  }
}

// ------- combine partials (plain sums; static max) + q1 + LN2 -> h -----
__device__ __forceinline__ float blk_sum256(float v, volatile float* red) {
  int tid = threadIdx.x;
#pragma unroll
  for (int o = 32; o; o >>= 1) v += __shfl_xor(v, o);
  __syncthreads();
  if ((tid & 63) == 0) red[tid >> 6] = v;
  __syncthreads();
  return red[0] + red[1] + red[2] + red[3];
}

__global__ __launch_bounds__(256) void combine_ln2(
    const unsigned short* __restrict__ Op, const float* __restrict__ lp,
    const float* __restrict__ q0f, const float* __restrict__ g2, const float* __restrict__ b2,
    float* __restrict__ q1, unsigned short* __restrict__ hb)
{
  int q = blockIdx.x, tid = threadIdx.x;
  __shared__ float lS[HEADS * NCHUNK];
  __shared__ float red[4];
  for (int i = tid; i < HEADS * NCHUNK; i += 256)
    lS[i] = lp[(size_t)i * 128 + q];
  __syncthreads();
  float vals[3];
#pragma unroll
  for (int ii = 0; ii < 3; ++ii) {
    int c = tid + ii * 256;
    int h = c >> 6, d = c & 63;
    float num = 0.f, den = 0.f;
    for (int cc = 0; cc < NCHUNK; ++cc) {
      den += lS[h * NCHUNK + cc];
      num += bf2f(Op[((size_t)(h * NCHUNK + cc) * 128 + q) * 64 + d]);
    }
    float ctx = 0.5f * num / den;
    float v = q0f[(size_t)q * DIM + c] + ctx;
    q1[(size_t)q * DIM + c] = v;
    vals[ii] = v;
  }
  float s = blk_sum256(vals[0] + vals[1] + vals[2], red);
  float mean = s * (1.f / 768.f);
  float d0 = vals[0] - mean, d1 = vals[1] - mean, d2 = vals[2] - mean;
  float ss = blk_sum256(d0 * d0 + d1 * d1 + d2 * d2, red);
  float rs = rsqrtf(ss * (1.f / 768.f) + 1e-5f);
#pragma unroll
  for (int ii = 0; ii < 3; ++ii) {
    int c = tid + ii * 256;
    hb[(size_t)q * DIM + c] = f2bf((vals[ii] - mean) * rs * g2[c] + b2[c]);
  }
}

// ------------------------------- host -----------------------------------
extern "C" void kernel_launch(void* const* d_in, const int* in_sizes, int n_in,
                              void* d_out, int out_size, void* d_ws, size_t ws_size,
                              hipStream_t stream) {
  const float* x   = (const float*)d_in[0];
  const float* cls = (const float*)d_in[1];
  const float* g1  = (const float*)d_in[2];
  const float* b1  = (const float*)d_in[3];
  const float* g2  = (const float*)d_in[4];
  const float* b2  = (const float*)d_in[5];
  const float* Wq  = (const float*)d_in[6];
  const float* Wk  = (const float*)d_in[7];
  const float* Wv  = (const float*)d_in[8];
  const float* fcw = (const float*)d_in[13];
  const float* fcb = (const float*)d_in[14];
  const float* pw  = (const float*)d_in[15];
  const float* pb  = (const float*)d_in[16];

  char* ws = (char*)d_ws;
  size_t off = 0;
  auto alloc = [&](size_t bytes) {
    char* p = ws + off;
    off += (bytes + 255) & ~(size_t)255;
    return p;
  };
  unsigned short* xxb  = (unsigned short*)alloc((size_t)ROWS_ALL * DIM * 2);
  float*          q0f  = (float*)alloc((size_t)NB * DIM * 4);
  unsigned short* Kbf  = (unsigned short*)alloc((size_t)ROWS_KV * DIM * 2);
  unsigned short* Vtb  = (unsigned short*)alloc((size_t)DIM * ROWS_KV * 2);
  unsigned short* Qbf  = (unsigned short*)alloc((size_t)NB * DIM * 2);
  unsigned short* wpk  = (unsigned short*)alloc((size_t)5 * DIM * DIM * 2);
  unsigned short* Opar = (unsigned short*)alloc((size_t)HEADS * NCHUNK * 128 * 64 * 2);
  float*          lpar = (float*)alloc((size_t)HEADS * NCHUNK * 128 * 4);
  float*          q1   = (float*)alloc((size_t)NB * DIM * 4);
  unsigned short* hb   = (unsigned short*)alloc((size_t)NB * DIM * 2);
  unsigned short* m1b  = (unsigned short*)alloc((size_t)NB * DIM * 2);

  unsigned short* Wqb = wpk;
  unsigned short* Wkb = wpk + (size_t)1 * DIM * DIM;
  unsigned short* Wvb = wpk + (size_t)2 * DIM * DIM;
  unsigned short* fwb = wpk + (size_t)3 * DIM * DIM;
  unsigned short* pwb = wpk + (size_t)4 * DIM * DIM;

  // fused LN1 + weight casts (6304 LN blocks + 2880 cast blocks)
  ln1_cast<<<ROWS_ALL / 4 + 2880, 256, 0, stream>>>(
      x, cls, g1, b1, xxb, q0f, Wq, Wk, Wv, fcw, pw, wpk);

  // fused K / V^T / Q projections (2358 blocks)
  gemm_fused<<<1176 + 1176 + 6, 256, 0, stream>>>(
      xxb + (size_t)NB * DIM, Wkb, Kbf, Wvb, Vtb, xxb, Wqb, Qbf);

  attn_partial<<<HEADS * NCHUNK, 256, 0, stream>>>(Qbf, Kbf, Vtb, Opar, lpar);
  combine_ln2<<<NB, 256, 0, stream>>>(Opar, lpar, q0f, g2, b2, q1, hb);

  // m1 = silu(h @ fc_w^T + fc_b)
  gemm_bt64<1><<<dim3(DIM / 128, 1), 256, 0, stream>>>(
      hb, fwb, m1b, NB, DIM, DIM, fcb, nullptr);
  // out = q1 + m1 @ proj_w^T + proj_b
  gemm_bt64<2><<<dim3(DIM / 128, 1), 256, 0, stream>>>(
      m1b, pwb, d_out, NB, DIM, DIM, pb, q1);
}

// Round 13
// 169.012 us; speedup vs baseline: 2.3714x; 2.3714x over previous
//
#include <hip/hip_runtime.h>

#define DIM 768
#define HEADS 12
#define HD 64
#define NB 128
#define ROWS_ALL 25216   // 197*128
#define ROWS_KV  25088   // 196*128
#define NCHUNK 64        // chunks per head; chunk c covers key-tiles [49c/8, 49(c+1)/8)

typedef __attribute__((ext_vector_type(8))) short short8;
typedef __attribute__((ext_vector_type(4))) short short4v;
typedef __attribute__((ext_vector_type(4))) float f32x4;
typedef __attribute__((ext_vector_type(4))) unsigned int uint4v;

__device__ __forceinline__ unsigned short f2bf(float f) {
  union { float f; unsigned u; } a; a.f = f;
  return (unsigned short)((a.u + 0x7fffu + ((a.u >> 16) & 1u)) >> 16);
}
__device__ __forceinline__ float bf2f(unsigned short u) {
  union { unsigned u; float f; } a; a.u = ((unsigned)u) << 16;
  return a.f;
}

__device__ __forceinline__ void gload16(const void* g, void* l) {
  __builtin_amdgcn_global_load_lds(
      (__attribute__((address_space(1))) void*)g,
      (__attribute__((address_space(3))) void*)l, 16, 0, 0);
}

// ------ fused: LN1 over concat([cls,x]) -> bf16 xx + f32 q0; cast 5 W ---
__global__ __launch_bounds__(256) void ln1_cast(
    const float* __restrict__ x, const float* __restrict__ cls,
    const float* __restrict__ g, const float* __restrict__ b,
    unsigned short* __restrict__ xx, float* __restrict__ q0f,
    const float* __restrict__ Wq, const float* __restrict__ Wk,
    const float* __restrict__ Wv, const float* __restrict__ fcw,
    const float* __restrict__ pw, unsigned short* __restrict__ wpk)
{
  int blk = blockIdx.x, tid = threadIdx.x;
  if (blk < ROWS_ALL / 4) {
    int row = blk * 4 + (tid >> 6);
    int lane = tid & 63;
    const float* src = (row < NB) ? (cls + (size_t)row * DIM)
                                  : (x + (size_t)(row - NB) * DIM);
    float4 v[3];
    float s = 0.f;
#pragma unroll
    for (int i = 0; i < 3; ++i) {
      v[i] = ((const float4*)src)[lane + 64 * i];
      s += v[i].x + v[i].y + v[i].z + v[i].w;
    }
#pragma unroll
    for (int o = 32; o; o >>= 1) s += __shfl_xor(s, o);
    float mean = s * (1.f / 768.f);
    float ss = 0.f;
#pragma unroll
    for (int i = 0; i < 3; ++i) {
      float a0 = v[i].x - mean, a1 = v[i].y - mean, a2 = v[i].z - mean, a3 = v[i].w - mean;
      ss += a0 * a0 + a1 * a1 + a2 * a2 + a3 * a3;
    }
#pragma unroll
    for (int o = 32; o; o >>= 1) ss += __shfl_xor(ss, o);
    float rs = rsqrtf(ss * (1.f / 768.f) + 1e-5f);
#pragma unroll
    for (int i = 0; i < 3; ++i) {
      int c4 = lane + 64 * i;
      float4 gv = ((const float4*)g)[c4];
      float4 bv = ((const float4*)b)[c4];
      float o0 = (v[i].x - mean) * rs * gv.x + bv.x;
      float o1 = (v[i].y - mean) * rs * gv.y + bv.y;
      float o2 = (v[i].z - mean) * rs * gv.z + bv.z;
      float o3 = (v[i].w - mean) * rs * gv.w + bv.w;
      ushort4 u; u.x = f2bf(o0); u.y = f2bf(o1); u.z = f2bf(o2); u.w = f2bf(o3);
      ((ushort4*)(xx + (size_t)row * DIM))[c4] = u;
      if (row < NB) {
        float4 fo; fo.x = o0; fo.y = o1; fo.z = o2; fo.w = o3;
        ((float4*)(q0f + (size_t)row * DIM))[c4] = fo;
      }
    }
  } else {
    int idx = blk - ROWS_ALL / 4;          // [0, 2880)
    int w = idx / 576;                     // matrix id, uniform per block
    int j4 = (idx % 576) * 256 + tid;      // float4 index within matrix
    const float* s = (w == 0) ? Wq : (w == 1) ? Wk : (w == 2) ? Wv
                   : (w == 3) ? fcw : pw;
    float4 v = ((const float4*)s)[j4];
    ushort4 u; u.x = f2bf(v.x); u.y = f2bf(v.y); u.z = f2bf(v.z); u.w = f2bf(v.w);
    ((ushort4*)(wpk + (size_t)w * (DIM * DIM)))[j4] = u;
  }
}

// ======= fused QKV projection GEMMs: m97-style 128x128, BK=32 ===========
// Best-measured variant (87.6us, 4 blocks/CU, ~670 TF). GEMM schedule
// search CLOSED: six variants (2ph / dbuf+vmcnt / 1-barrier / 256^2-8phase
// / reg-direct-weights) all measured 87.6-331us; this is the optimum at
// K=768. Round-12 lesson: global->reg weight streaming under a reg cap
// spills to scratch (WRITE_SIZE 75->694 MB, 3.8x regression).
// Q-job output is pre-scaled by log2e/8 for attn's exp2.
__global__ __launch_bounds__(256, 4) void gemm_fused(
    const unsigned short* __restrict__ xxkv, const unsigned short* __restrict__ Wkb,
    unsigned short* __restrict__ Kbf,
    const unsigned short* __restrict__ Wvb, unsigned short* __restrict__ Vtb,
    const unsigned short* __restrict__ xxall, const unsigned short* __restrict__ Wqb,
    unsigned short* __restrict__ Qbf)
{
  __shared__ unsigned short Asm[128 * 32];   // 8KB
  __shared__ unsigned short Bsm[128 * 32];   // 8KB
  int tid = threadIdx.x, wid = tid >> 6, lane = tid & 63;
  int l15 = lane & 15, l4 = lane >> 4;

  int nwg = gridDim.x;
  int bid = blockIdx.x;
  int q8 = nwg >> 3, r8 = nwg & 7;
  int xcd = bid & 7, rank = bid >> 3;
  int swz = (xcd < r8 ? xcd * (q8 + 1) : r8 * (q8 + 1) + (xcd - r8) * q8) + rank;

  const unsigned short *A, *Bt;
  unsigned short* C;
  int N, row0, col0;
  const int K = DIM;
  if (swz < 1176) {                 // K = xx_kv @ Wk^T
    A = xxkv; Bt = Wkb; C = Kbf; N = DIM;
    row0 = (swz / 6) * 128; col0 = (swz % 6) * 128;
  } else if (swz < 2352) {          // V^T = Wv @ xx_kv^T
    int inner = swz - 1176;
    A = Wvb; Bt = xxkv; C = Vtb; N = ROWS_KV;
    row0 = (inner % 6) * 128; col0 = (inner / 6) * 128;
  } else {                          // Q = xx_cls @ Wq^T (pre-scaled)
    int inner = swz - 2352;
    A = xxall; Bt = Wqb; C = Qbf; N = DIM;
    row0 = 0; col0 = inner * 128;
  }
  float csc = (swz >= 2352) ? 0.18033688011112042f : 1.0f;  // log2e/8 for Q

  int srow = tid >> 2;
  int sq = tid & 3;
  int sb = sq ^ ((srow >> 1) & 3);
  const char* Ag = (const char*)A + (size_t)(row0 + srow) * K * 2 + sb * 16;
  const char* Bg = (const char*)Bt + (size_t)(col0 + srow) * K * 2 + sb * 16;
  size_t rstep64 = (size_t)64 * K * 2;

  f32x4 acc[4][4] = {};
  int wr = (wid >> 1) * 64, wc = (wid & 1) * 64;
  const int nk = K >> 5;            // 24 K-steps of BK=32
  for (int t = 0; t < nk; ++t) {
    {
      const char* a0 = Ag + (size_t)t * 64;
      const char* b0 = Bg + (size_t)t * 64;
      char* la = (char*)Asm + wid * 1024;
      char* lb = (char*)Bsm + wid * 1024;
      gload16(a0,           la);
      gload16(a0 + rstep64, la + 4096);
      gload16(b0,           lb);
      gload16(b0 + rstep64, lb + 4096);
    }
    asm volatile("s_waitcnt vmcnt(0)" ::: "memory");
    __builtin_amdgcn_s_barrier();
    asm volatile("" ::: "memory");
    short8 aF[4], bF[4];
#pragma unroll
    for (int m = 0; m < 4; ++m) {
      int row = wr + m * 16 + l15;
      aF[m] = *(const short8*)((const char*)Asm + row * 64 + ((l4 ^ ((row >> 1) & 3)) << 4));
    }
#pragma unroll
    for (int n = 0; n < 4; ++n) {
      int row = wc + n * 16 + l15;
      bF[n] = *(const short8*)((const char*)Bsm + row * 64 + ((l4 ^ ((row >> 1) & 3)) << 4));
    }
    __builtin_amdgcn_s_setprio(1);
#pragma unroll
    for (int m = 0; m < 4; ++m)
#pragma unroll
      for (int n = 0; n < 4; ++n)
        acc[m][n] = __builtin_amdgcn_mfma_f32_16x16x32_bf16(aF[m], bF[n], acc[m][n], 0, 0, 0);
    __builtin_amdgcn_s_setprio(0);
    asm volatile("" ::: "memory");
    __builtin_amdgcn_s_barrier();
    asm volatile("" ::: "memory");
  }
#pragma unroll
  for (int m = 0; m < 4; ++m)
#pragma unroll
    for (int n = 0; n < 4; ++n)
#pragma unroll
      for (int r = 0; r < 4; ++r) {
        int rr = row0 + wr + m * 16 + l4 * 4 + r;
        int cc = col0 + wc + n * 16 + l15;
        C[(size_t)rr * N + cc] = f2bf(acc[m][n][r] * csc);
      }
}

// ======= 128x128 tile GEMM (small M epilogue cases), BK=64, 1 barrier ===
// EPI 1: +bias, silu(1.702), bf16 store; 2: +bias +addsrc, f32 store
template <int EPI>
__global__ __launch_bounds__(256, 2) void gemm_bt64(
    const unsigned short* __restrict__ A, const unsigned short* __restrict__ Bt,
    void* __restrict__ Cout, int M, int N, int K,
    const float* __restrict__ bias, const float* __restrict__ addsrc)
{
  __shared__ unsigned short Asm[2][128 * 64];
  __shared__ unsigned short Bsm[2][128 * 64];
  int tid = threadIdx.x, wid = tid >> 6, lane = tid & 63;
  int l15 = lane & 15, l4 = lane >> 4;
  int row0 = blockIdx.y * 128, col0 = blockIdx.x * 128;

  int srow = tid >> 3;
  int scol = ((tid & 7) ^ (srow & 7)) << 4;
  const char* Ag = (const char*)A + (size_t)(row0 + srow) * K * 2 + scol;
  const char* Bg = (const char*)Bt + (size_t)(col0 + srow) * K * 2 + scol;
  size_t rstep32 = (size_t)32 * K * 2;

#define STAGE(buf, kt) do {                                           \
    const char* a0 = Ag + (size_t)(kt) * 128;                         \
    const char* b0 = Bg + (size_t)(kt) * 128;                         \
    char* la = (char*)Asm[buf] + wid * 1024;                          \
    char* lb = (char*)Bsm[buf] + wid * 1024;                          \
    gload16(a0,                la);                                   \
    gload16(a0 + rstep32,      la + 4096);                            \
    gload16(a0 + 2 * rstep32,  la + 8192);                            \
    gload16(a0 + 3 * rstep32,  la + 12288);                           \
    gload16(b0,                lb);                                   \
    gload16(b0 + rstep32,      lb + 4096);                            \
    gload16(b0 + 2 * rstep32,  lb + 8192);                            \
    gload16(b0 + 3 * rstep32,  lb + 12288);                           \
  } while (0)

  f32x4 acc[4][4] = {};
  int wr = (wid >> 1) * 64, wc = (wid & 1) * 64;
  int nk = K >> 6;                 // BK=64
  STAGE(0, 0);
  for (int t = 0; t < nk; ++t) {
    int cur = t & 1;
    __builtin_amdgcn_s_barrier();
    asm volatile("" ::: "memory");
    if (t + 1 < nk) {
      STAGE(cur ^ 1, t + 1);
      asm volatile("s_waitcnt vmcnt(8)" ::: "memory");
    } else {
      asm volatile("s_waitcnt vmcnt(0)" ::: "memory");
    }
    const char* Ab = (const char*)Asm[cur];
    const char* Bb = (const char*)Bsm[cur];
#pragma unroll
    for (int kk = 0; kk < 2; ++kk) {
      short8 aF[4], bF[4];
#pragma unroll
      for (int m = 0; m < 4; ++m) {
        int row = wr + m * 16 + l15;
        aF[m] = *(const short8*)(Ab + row * 128 + ((((kk << 2) | l4) ^ (row & 7)) << 4));
      }
#pragma unroll
      for (int n = 0; n < 4; ++n) {
        int row = wc + n * 16 + l15;
        bF[n] = *(const short8*)(Bb + row * 128 + ((((kk << 2) | l4) ^ (row & 7)) << 4));
      }
#pragma unroll
      for (int m = 0; m < 4; ++m)
#pragma unroll
        for (int n = 0; n < 4; ++n)
          acc[m][n] = __builtin_amdgcn_mfma_f32_16x16x32_bf16(aF[m], bF[n], acc[m][n], 0, 0, 0);
    }
    asm volatile("" ::: "memory");
  }
#undef STAGE
#pragma unroll
  for (int m = 0; m < 4; ++m)
#pragma unroll
    for (int n = 0; n < 4; ++n)
#pragma unroll
      for (int r = 0; r < 4; ++r) {
        int rr = row0 + wr + m * 16 + l4 * 4 + r;
        int cc = col0 + wc + n * 16 + l15;
        float v = acc[m][n][r];
        if (EPI == 1) {
          v += bias[cc];
          v = v / (1.f + __expf(-1.702f * v));
          ((unsigned short*)Cout)[(size_t)rr * N + cc] = f2bf(v);
        } else {
          v += bias[cc] + addsrc[(size_t)rr * N + cc];
          ((float*)Cout)[(size_t)rr * N + cc] = v;
        }
      }
}

// ---------------- flash-decode attention partials (swapped QK^T) --------
// Static-max softmax; Q pre-scaled by log2e/8 in gemm_fused, so
// p = exp2(S_scaled) directly — no per-score multiply.
__global__ __launch_bounds__(256, 4) void attn_partial(
    const unsigned short* __restrict__ Qb, const unsigned short* __restrict__ Kb,
    const unsigned short* __restrict__ Vt,
    unsigned short* __restrict__ Op, float* __restrict__ lp)
{
  __shared__ unsigned short Klds[2][64 * 64];
  __shared__ unsigned short Vlds[2][64 * 64];
  int tid = threadIdx.x, wid = tid >> 6, lane = tid & 63;
  int l15 = lane & 15, l4 = lane >> 4;
  int head = blockIdx.x >> 6, chunk = blockIdx.x & 63;
  int t0 = (49 * chunk) >> 3;
  int nkt = ((49 * (chunk + 1)) >> 3) - t0;   // 6 or 7

  short8 bQ[2][2];
#pragma unroll
  for (int m = 0; m < 2; ++m)
#pragma unroll
    for (int kk = 0; kk < 2; ++kk) {
      int qrow = wid * 32 + m * 16 + l15;
      bQ[m][kk] = *(const short8*)(Qb + (size_t)qrow * DIM + head * HD + kk * 32 + l4 * 8);
    }
  f32x4 accO[2][4] = {};
  float lrun[2] = { 0.f, 0.f };

  int srow = tid >> 3;                       // 0..31 within a 32-row pass
  int sblk = (tid & 7) ^ (srow & 7);
  const char* Kg = (const char*)(Kb + (size_t)(t0 * 64 + srow) * DIM + head * HD) + sblk * 16;
  const char* Vg = (const char*)(Vt + (size_t)(head * HD + srow) * ROWS_KV + t0 * 64) + sblk * 16;

#define STAGEKV(buf, kt) do {                                         \
    const char* k0 = Kg + (size_t)(kt) * 64 * DIM * 2;                \
    const char* v0 = Vg + (size_t)(kt) * 128;                         \
    char* lk = (char*)Klds[buf] + wid * 1024;                         \
    char* lv = (char*)Vlds[buf] + wid * 1024;                         \
    gload16(k0,                        lk);                           \
    gload16(k0 + (size_t)32 * DIM * 2, lk + 4096);                    \
    gload16(v0,                        lv);                           \
    gload16(v0 + (size_t)32 * ROWS_KV * 2, lv + 4096);                \
  } while (0)

  STAGEKV(0, 0);
  for (int kt = 0; kt < nkt; ++kt) {
    int cur = kt & 1;
    __builtin_amdgcn_s_barrier();   // all waves done reading buf[cur^1]
    asm volatile("" ::: "memory");
    if (kt + 1 < nkt) {
      STAGEKV(cur ^ 1, kt + 1);
      asm volatile("s_waitcnt vmcnt(4)" ::: "memory");
    } else {
      asm volatile("s_waitcnt vmcnt(0)" ::: "memory");
    }

    // S^T[key][q]: sc[n][m][r] = Ssc[q0+m*16+l15][key = n*16 + l4*4 + r]
    f32x4 sc[4][2] = {};
    __builtin_amdgcn_s_setprio(1);
#pragma unroll
    for (int kk = 0; kk < 2; ++kk) {
      short8 aK[4];
#pragma unroll
      for (int n = 0; n < 4; ++n) {
        int krow = n * 16 + l15;
        int blk = ((kk << 2) | l4) ^ (krow & 7);
        aK[n] = *(const short8*)((const char*)Klds[cur] + krow * 128 + blk * 16);
      }
#pragma unroll
      for (int n = 0; n < 4; ++n)
#pragma unroll
        for (int m = 0; m < 2; ++m)
          sc[n][m] = __builtin_amdgcn_mfma_f32_16x16x32_bf16(aK[n], bQ[m][kk], sc[n][m], 0, 0, 0);
    }
    __builtin_amdgcn_s_setprio(0);

    // static-max softmax: p = 2^(S_scaled); sum; pack bf16 via cvt_pk
    short8 pB[2][2];
#pragma unroll
    for (int m = 0; m < 2; ++m) {
      float rsum = 0.f;
#pragma unroll
      for (int n = 0; n < 4; ++n)
#pragma unroll
        for (int r = 0; r < 4; ++r) {
          float p;
          asm("v_exp_f32 %0, %1" : "=v"(p) : "v"(sc[n][m][r]));
          sc[n][m][r] = p;
          rsum += p;
        }
      rsum += __shfl_xor(rsum, 16);
      rsum += __shfl_xor(rsum, 32);
      lrun[m] += rsum;
#pragma unroll
      for (int kk2 = 0; kk2 < 2; ++kk2) {
        uint4v pw;
#pragma unroll
        for (int w = 0; w < 4; ++w) {
          int n = 2 * kk2 + (w >> 1);
          int r0 = (w & 1) * 2;
          unsigned int u;
          asm("v_cvt_pk_bf16_f32 %0, %1, %2"
              : "=v"(u) : "v"(sc[n][m][r0]), "v"(sc[n][m][r0 + 1]));
          pw[w] = u;
        }
        pB[m][kk2] = __builtin_bit_cast(short8, pw);
      }
    }

    // O^T += V'^T P'
    __builtin_amdgcn_s_setprio(1);
#pragma unroll
    for (int kk2 = 0; kk2 < 2; ++kk2) {
      short8 aV[4];
#pragma unroll
      for (int nb = 0; nb < 4; ++nb) {
        int row = nb * 16 + l15;
        int blk1 = (kk2 << 2) | (l4 >> 1);
        int in1 = (l4 & 1) << 3;
        const char* vb = (const char*)Vlds[cur] + row * 128;
        short4v lo = *(const short4v*)(vb + (((blk1 ^ (row & 7)) << 4) | in1));
        short4v hi = *(const short4v*)(vb + ((((blk1 + 2) ^ (row & 7)) << 4) | in1));
        aV[nb] = __builtin_shufflevector(lo, hi, 0, 1, 2, 3, 4, 5, 6, 7);
      }
#pragma unroll
      for (int m = 0; m < 2; ++m)
#pragma unroll
        for (int nb = 0; nb < 4; ++nb)
          accO[m][nb] = __builtin_amdgcn_mfma_f32_16x16x32_bf16(aV[nb], pB[m][kk2], accO[m][nb], 0, 0, 0);
    }
    __builtin_amdgcn_s_setprio(0);
    asm volatile("" ::: "memory");
  }
#undef STAGEKV
  size_t pb = (size_t)(head * NCHUNK + chunk) * 128;
#pragma unroll
  for (int m = 0; m < 2; ++m) {
    int q = wid * 32 + m * 16 + l15;
#pragma unroll
    for (int nb = 0; nb < 4; ++nb) {
      ushort4 o;
      o.x = f2bf(accO[m][nb][0]); o.y = f2bf(accO[m][nb][1]);
      o.z = f2bf(accO[m][nb][2]); o.w = f2bf(accO[m][nb][3]);
      *(ushort4*)(Op + (pb + q) * 64 + nb * 16 + l4 * 4) = o;
    }
    if (l4 == 0) {
      lp[pb + q] = lrun[m];
    }
  }
}

// ------- combine partials (plain sums; static max) + q1 + LN2 -> h -----
__device__ __forceinline__ float blk_sum256(float v, volatile float* red) {
  int tid = threadIdx.x;
#pragma unroll
  for (int o = 32; o; o >>= 1) v += __shfl_xor(v, o);
  __syncthreads();
  if ((tid & 63) == 0) red[tid >> 6] = v;
  __syncthreads();
  return red[0] + red[1] + red[2] + red[3];
}

__global__ __launch_bounds__(256) void combine_ln2(
    const unsigned short* __restrict__ Op, const float* __restrict__ lp,
    const float* __restrict__ q0f, const float* __restrict__ g2, const float* __restrict__ b2,
    float* __restrict__ q1, unsigned short* __restrict__ hb)
{
  int q = blockIdx.x, tid = threadIdx.x;
  __shared__ float lS[HEADS * NCHUNK];
  __shared__ float red[4];
  for (int i = tid; i < HEADS * NCHUNK; i += 256)
    lS[i] = lp[(size_t)i * 128 + q];
  __syncthreads();
  float vals[3];
#pragma unroll
  for (int ii = 0; ii < 3; ++ii) {
    int c = tid + ii * 256;
    int h = c >> 6, d = c & 63;
    float num = 0.f, den = 0.f;
    for (int cc = 0; cc < NCHUNK; ++cc) {
      den += lS[h * NCHUNK + cc];
      num += bf2f(Op[((size_t)(h * NCHUNK + cc) * 128 + q) * 64 + d]);
    }
    float ctx = 0.5f * num / den;
    float v = q0f[(size_t)q * DIM + c] + ctx;
    q1[(size_t)q * DIM + c] = v;
    vals[ii] = v;
  }
  float s = blk_sum256(vals[0] + vals[1] + vals[2], red);
  float mean = s * (1.f / 768.f);
  float d0 = vals[0] - mean, d1 = vals[1] - mean, d2 = vals[2] - mean;
  float ss = blk_sum256(d0 * d0 + d1 * d1 + d2 * d2, red);
  float rs = rsqrtf(ss * (1.f / 768.f) + 1e-5f);
#pragma unroll
  for (int ii = 0; ii < 3; ++ii) {
    int c = tid + ii * 256;
    hb[(size_t)q * DIM + c] = f2bf((vals[ii] - mean) * rs * g2[c] + b2[c]);
  }
}

// ------------------------------- host -----------------------------------
extern "C" void kernel_launch(void* const* d_in, const int* in_sizes, int n_in,
                              void* d_out, int out_size, void* d_ws, size_t ws_size,
                              hipStream_t stream) {
  const float* x   = (const float*)d_in[0];
  const float* cls = (const float*)d_in[1];
  const float* g1  = (const float*)d_in[2];
  const float* b1  = (const float*)d_in[3];
  const float* g2  = (const float*)d_in[4];
  const float* b2  = (const float*)d_in[5];
  const float* Wq  = (const float*)d_in[6];
  const float* Wk  = (const float*)d_in[7];
  const float* Wv  = (const float*)d_in[8];
  const float* fcw = (const float*)d_in[13];
  const float* fcb = (const float*)d_in[14];
  const float* pw  = (const float*)d_in[15];
  const float* pb  = (const float*)d_in[16];

  char* ws = (char*)d_ws;
  size_t off = 0;
  auto alloc = [&](size_t bytes) {
    char* p = ws + off;
    off += (bytes + 255) & ~(size_t)255;
    return p;
  };
  unsigned short* xxb  = (unsigned short*)alloc((size_t)ROWS_ALL * DIM * 2);
  float*          q0f  = (float*)alloc((size_t)NB * DIM * 4);
  unsigned short* Kbf  = (unsigned short*)alloc((size_t)ROWS_KV * DIM * 2);
  unsigned short* Vtb  = (unsigned short*)alloc((size_t)DIM * ROWS_KV * 2);
  unsigned short* Qbf  = (unsigned short*)alloc((size_t)NB * DIM * 2);
  unsigned short* wpk  = (unsigned short*)alloc((size_t)5 * DIM * DIM * 2);
  unsigned short* Opar = (unsigned short*)alloc((size_t)HEADS * NCHUNK * 128 * 64 * 2);
  float*          lpar = (float*)alloc((size_t)HEADS * NCHUNK * 128 * 4);
  float*          q1   = (float*)alloc((size_t)NB * DIM * 4);
  unsigned short* hb   = (unsigned short*)alloc((size_t)NB * DIM * 2);
  unsigned short* m1b  = (unsigned short*)alloc((size_t)NB * DIM * 2);

  unsigned short* Wqb = wpk;
  unsigned short* Wkb = wpk + (size_t)1 * DIM * DIM;
  unsigned short* Wvb = wpk + (size_t)2 * DIM * DIM;
  unsigned short* fwb = wpk + (size_t)3 * DIM * DIM;
  unsigned short* pwb = wpk + (size_t)4 * DIM * DIM;

  // fused LN1 + weight casts (6304 LN blocks + 2880 cast blocks)
  ln1_cast<<<ROWS_ALL / 4 + 2880, 256, 0, stream>>>(
      x, cls, g1, b1, xxb, q0f, Wq, Wk, Wv, fcw, pw, wpk);

  // fused K / V^T / Q projections (2358 blocks)
  gemm_fused<<<1176 + 1176 + 6, 256, 0, stream>>>(
      xxb + (size_t)NB * DIM, Wkb, Kbf, Wvb, Vtb, xxb, Wqb, Qbf);

  attn_partial<<<HEADS * NCHUNK, 256, 0, stream>>>(Qbf, Kbf, Vtb, Opar, lpar);
  combine_ln2<<<NB, 256, 0, stream>>>(Opar, lpar, q0f, g2, b2, q1, hb);

  // m1 = silu(h @ fc_w^T + fc_b)
  gemm_bt64<1><<<dim3(DIM / 128, 1), 256, 0, stream>>>(
      hb, fwb, m1b, NB, DIM, DIM, fcb, nullptr);
  // out = q1 + m1 @ proj_w^T + proj_b
  gemm_bt64<2><<<dim3(DIM / 128, 1), 256, 0, stream>>>(
      m1b, pwb, d_out, NB, DIM, DIM, pb, q1);
}

// Round 14
// 138.351 us; speedup vs baseline: 2.8969x; 1.2216x over previous
//
#include <hip/hip_runtime.h>

#define DIM 768
#define HEADS 12
#define HD 64
#define NB 128
#define ROWS_ALL 25216   // 197*128
#define ROWS_KV  25088   // 196*128
#define NCHUNK 64        // chunks per head; chunk c covers key-tiles [49c/8, 49(c+1)/8)

typedef __attribute__((ext_vector_type(8))) short short8;
typedef __attribute__((ext_vector_type(4))) short short4v;
typedef __attribute__((ext_vector_type(4))) float f32x4;
typedef __attribute__((ext_vector_type(4))) unsigned int uint4v;
typedef long long i64;

__device__ __forceinline__ unsigned short f2bf(float f) {
  union { float f; unsigned u; } a; a.f = f;
  return (unsigned short)((a.u + 0x7fffu + ((a.u >> 16) & 1u)) >> 16);
}
__device__ __forceinline__ float bf2f(unsigned short u) {
  union { unsigned u; float f; } a; a.u = ((unsigned)u) << 16;
  return a.f;
}
// pack 4 f32 -> 4 fp8 e4m3 (OCP on gfx950)
__device__ __forceinline__ unsigned pk_fp8x4(float a, float b, float c, float d) {
  int p = __builtin_amdgcn_cvt_pk_fp8_f32(a, b, 0, false);
  p = __builtin_amdgcn_cvt_pk_fp8_f32(c, d, p, true);
  return (unsigned)p;
}

__device__ __forceinline__ void gload16(const void* g, void* l) {
  __builtin_amdgcn_global_load_lds(
      (__attribute__((address_space(1))) void*)g,
      (__attribute__((address_space(3))) void*)l, 16, 0, 0);
}

// ------ fused: LN1 -> fp8 xx + f32 q0; cast Wq/Wk/Wv->fp8, fcw/pw->bf16 --
__global__ __launch_bounds__(256) void ln1_cast(
    const float* __restrict__ x, const float* __restrict__ cls,
    const float* __restrict__ g, const float* __restrict__ b,
    unsigned char* __restrict__ xx8, float* __restrict__ q0f,
    const float* __restrict__ Wq, const float* __restrict__ Wk,
    const float* __restrict__ Wv, const float* __restrict__ fcw,
    const float* __restrict__ pw,
    unsigned char* __restrict__ w8, unsigned short* __restrict__ wbf)
{
  int blk = blockIdx.x, tid = threadIdx.x;
  if (blk < ROWS_ALL / 4) {
    int row = blk * 4 + (tid >> 6);
    int lane = tid & 63;
    const float* src = (row < NB) ? (cls + (size_t)row * DIM)
                                  : (x + (size_t)(row - NB) * DIM);
    float4 v[3];
    float s = 0.f;
#pragma unroll
    for (int i = 0; i < 3; ++i) {
      v[i] = ((const float4*)src)[lane + 64 * i];
      s += v[i].x + v[i].y + v[i].z + v[i].w;
    }
#pragma unroll
    for (int o = 32; o; o >>= 1) s += __shfl_xor(s, o);
    float mean = s * (1.f / 768.f);
    float ss = 0.f;
#pragma unroll
    for (int i = 0; i < 3; ++i) {
      float a0 = v[i].x - mean, a1 = v[i].y - mean, a2 = v[i].z - mean, a3 = v[i].w - mean;
      ss += a0 * a0 + a1 * a1 + a2 * a2 + a3 * a3;
    }
#pragma unroll
    for (int o = 32; o; o >>= 1) ss += __shfl_xor(ss, o);
    float rs = rsqrtf(ss * (1.f / 768.f) + 1e-5f);
#pragma unroll
    for (int i = 0; i < 3; ++i) {
      int c4 = lane + 64 * i;
      float4 gv = ((const float4*)g)[c4];
      float4 bv = ((const float4*)b)[c4];
      float o0 = (v[i].x - mean) * rs * gv.x + bv.x;
      float o1 = (v[i].y - mean) * rs * gv.y + bv.y;
      float o2 = (v[i].z - mean) * rs * gv.z + bv.z;
      float o3 = (v[i].w - mean) * rs * gv.w + bv.w;
      ((unsigned*)(xx8 + (size_t)row * DIM))[c4] = pk_fp8x4(o0, o1, o2, o3);
      if (row < NB) {
        float4 fo; fo.x = o0; fo.y = o1; fo.z = o2; fo.w = o3;
        ((float4*)(q0f + (size_t)row * DIM))[c4] = fo;
      }
    }
  } else {
    int idx = blk - ROWS_ALL / 4;          // [0, 2880)
    int w = idx / 576;                     // matrix id, uniform per block
    int j4 = (idx % 576) * 256 + tid;      // float4 index within matrix
    const float* s = (w == 0) ? Wq : (w == 1) ? Wk : (w == 2) ? Wv
                   : (w == 3) ? fcw : pw;
    float4 v = ((const float4*)s)[j4];
    if (w < 3) {
      ((unsigned*)(w8 + (size_t)w * (DIM * DIM)))[j4] = pk_fp8x4(v.x, v.y, v.z, v.w);
    } else {
      ushort4 u; u.x = f2bf(v.x); u.y = f2bf(v.y); u.z = f2bf(v.z); u.w = f2bf(v.w);
      ((ushort4*)(wbf + (size_t)(w - 3) * (DIM * DIM)))[j4] = u;
    }
  }
}

// ======= fused QKV projection GEMMs: 128x128 tile, FP8 inputs, BK=64 ====
// fp8 halves bytes/K: BK=64 in the same 8KB tile -> 12 K-steps (was 24),
// halving barriers/drains/gloads (the measured binding cost). LDS scheme
// identical to the bf16 64B-row layout; reads are ds_read_b64, 2-way (free).
// Outputs remain bf16 (Q pre-scaled by log2e/8 for attn's exp2).
__global__ __launch_bounds__(256, 4) void gemm_fused(
    const unsigned char* __restrict__ xxkv, const unsigned char* __restrict__ Wk8,
    unsigned short* __restrict__ Kbf,
    const unsigned char* __restrict__ Wv8, unsigned short* __restrict__ Vtb,
    const unsigned char* __restrict__ xxall, const unsigned char* __restrict__ Wq8,
    unsigned short* __restrict__ Qbf)
{
  __shared__ unsigned char Asm[128 * 64];   // 8KB
  __shared__ unsigned char Bsm[128 * 64];   // 8KB
  int tid = threadIdx.x, wid = tid >> 6, lane = tid & 63;
  int l15 = lane & 15, l4 = lane >> 4;

  int nwg = gridDim.x;
  int bid = blockIdx.x;
  int q8 = nwg >> 3, r8 = nwg & 7;
  int xcd = bid & 7, rank = bid >> 3;
  int swz = (xcd < r8 ? xcd * (q8 + 1) : r8 * (q8 + 1) + (xcd - r8) * q8) + rank;

  const unsigned char *A, *Bt;
  unsigned short* C;
  int N, row0, col0;
  const int K = DIM;                 // 768 fp8 bytes per row
  if (swz < 1176) {                  // K = xx_kv @ Wk^T
    A = xxkv; Bt = Wk8; C = Kbf; N = DIM;
    row0 = (swz / 6) * 128; col0 = (swz % 6) * 128;
  } else if (swz < 2352) {           // V^T = Wv @ xx_kv^T
    int inner = swz - 1176;
    A = Wv8; Bt = xxkv; C = Vtb; N = ROWS_KV;
    row0 = (inner % 6) * 128; col0 = (inner / 6) * 128;
  } else {                           // Q = xx_cls @ Wq^T (pre-scaled)
    int inner = swz - 2352;
    A = xxall; Bt = Wq8; C = Qbf; N = DIM;
    row0 = 0; col0 = inner * 128;
  }
  float csc = (swz >= 2352) ? 0.18033688011112042f : 1.0f;  // log2e/8 for Q

  int srow = tid >> 2;
  int sq = tid & 3;
  int sb = sq ^ ((srow >> 1) & 3);
  const unsigned char* Ag = A + (size_t)(row0 + srow) * K + sb * 16;
  const unsigned char* Bg = Bt + (size_t)(col0 + srow) * K + sb * 16;
  size_t rstep64 = (size_t)64 * K;

  f32x4 acc[4][4] = {};
  int wr = (wid >> 1) * 64, wc = (wid & 1) * 64;
  const int nk = K >> 6;             // 12 K-steps of BK=64 (64 bytes/row)
  for (int t = 0; t < nk; ++t) {
    {
      const unsigned char* a0 = Ag + (size_t)t * 64;
      const unsigned char* b0 = Bg + (size_t)t * 64;
      char* la = (char*)Asm + wid * 1024;
      char* lb = (char*)Bsm + wid * 1024;
      gload16(a0,           la);
      gload16(a0 + rstep64, la + 4096);
      gload16(b0,           lb);
      gload16(b0 + rstep64, lb + 4096);
    }
    asm volatile("s_waitcnt vmcnt(0)" ::: "memory");
    __builtin_amdgcn_s_barrier();
    asm volatile("" ::: "memory");
    i64 aF[4][2], bF[4][2];
#pragma unroll
    for (int m = 0; m < 4; ++m) {
      int row = wr + m * 16 + l15;
#pragma unroll
      for (int kk = 0; kk < 2; ++kk) {
        int blk = ((kk << 1) | (l4 >> 1)) ^ ((row >> 1) & 3);
        aF[m][kk] = *(const i64*)((const char*)Asm + row * 64 + (blk << 4) + ((l4 & 1) << 3));
      }
    }
#pragma unroll
    for (int n = 0; n < 4; ++n) {
      int row = wc + n * 16 + l15;
#pragma unroll
      for (int kk = 0; kk < 2; ++kk) {
        int blk = ((kk << 1) | (l4 >> 1)) ^ ((row >> 1) & 3);
        bF[n][kk] = *(const i64*)((const char*)Bsm + row * 64 + (blk << 4) + ((l4 & 1) << 3));
      }
    }
    __builtin_amdgcn_s_setprio(1);
#pragma unroll
    for (int kk = 0; kk < 2; ++kk)
#pragma unroll
      for (int m = 0; m < 4; ++m)
#pragma unroll
        for (int n = 0; n < 4; ++n)
          acc[m][n] = __builtin_amdgcn_mfma_f32_16x16x32_fp8_fp8(
              aF[m][kk], bF[n][kk], acc[m][n], 0, 0, 0);
    __builtin_amdgcn_s_setprio(0);
    asm volatile("" ::: "memory");
    __builtin_amdgcn_s_barrier();
    asm volatile("" ::: "memory");
  }
#pragma unroll
  for (int m = 0; m < 4; ++m)
#pragma unroll
    for (int n = 0; n < 4; ++n)
#pragma unroll
      for (int r = 0; r < 4; ++r) {
        int rr = row0 + wr + m * 16 + l4 * 4 + r;
        int cc = col0 + wc + n * 16 + l15;
        C[(size_t)rr * N + cc] = f2bf(acc[m][n][r] * csc);
      }
}

// ======= 128x128 tile GEMM (small M epilogue cases), BK=64, 1 barrier ===
// EPI 1: +bias, silu(1.702), bf16 store; 2: +bias +addsrc, f32 store
template <int EPI>
__global__ __launch_bounds__(256, 2) void gemm_bt64(
    const unsigned short* __restrict__ A, const unsigned short* __restrict__ Bt,
    void* __restrict__ Cout, int M, int N, int K,
    const float* __restrict__ bias, const float* __restrict__ addsrc)
{
  __shared__ unsigned short Asm[2][128 * 64];
  __shared__ unsigned short Bsm[2][128 * 64];
  int tid = threadIdx.x, wid = tid >> 6, lane = tid & 63;
  int l15 = lane & 15, l4 = lane >> 4;
  int row0 = blockIdx.y * 128, col0 = blockIdx.x * 128;

  int srow = tid >> 3;
  int scol = ((tid & 7) ^ (srow & 7)) << 4;
  const char* Ag = (const char*)A + (size_t)(row0 + srow) * K * 2 + scol;
  const char* Bg = (const char*)Bt + (size_t)(col0 + srow) * K * 2 + scol;
  size_t rstep32 = (size_t)32 * K * 2;

#define STAGE(buf, kt) do {                                           \
    const char* a0 = Ag + (size_t)(kt) * 128;                         \
    const char* b0 = Bg + (size_t)(kt) * 128;                         \
    char* la = (char*)Asm[buf] + wid * 1024;                          \
    char* lb = (char*)Bsm[buf] + wid * 1024;                          \
    gload16(a0,                la);                                   \
    gload16(a0 + rstep32,      la + 4096);                            \
    gload16(a0 + 2 * rstep32,  la + 8192);                            \
    gload16(a0 + 3 * rstep32,  la + 12288);                           \
    gload16(b0,                lb);                                   \
    gload16(b0 + rstep32,      lb + 4096);                            \
    gload16(b0 + 2 * rstep32,  lb + 8192);                            \
    gload16(b0 + 3 * rstep32,  lb + 12288);                           \
  } while (0)

  f32x4 acc[4][4] = {};
  int wr = (wid >> 1) * 64, wc = (wid & 1) * 64;
  int nk = K >> 6;                 // BK=64
  STAGE(0, 0);
  for (int t = 0; t < nk; ++t) {
    int cur = t & 1;
    __builtin_amdgcn_s_barrier();
    asm volatile("" ::: "memory");
    if (t + 1 < nk) {
      STAGE(cur ^ 1, t + 1);
      asm volatile("s_waitcnt vmcnt(8)" ::: "memory");
    } else {
      asm volatile("s_waitcnt vmcnt(0)" ::: "memory");
    }
    const char* Ab = (const char*)Asm[cur];
    const char* Bb = (const char*)Bsm[cur];
#pragma unroll
    for (int kk = 0; kk < 2; ++kk) {
      short8 aF[4], bF[4];
#pragma unroll
      for (int m = 0; m < 4; ++m) {
        int row = wr + m * 16 + l15;
        aF[m] = *(const short8*)(Ab + row * 128 + ((((kk << 2) | l4) ^ (row & 7)) << 4));
      }
#pragma unroll
      for (int n = 0; n < 4; ++n) {
        int row = wc + n * 16 + l15;
        bF[n] = *(const short8*)(Bb + row * 128 + ((((kk << 2) | l4) ^ (row & 7)) << 4));
      }
#pragma unroll
      for (int m = 0; m < 4; ++m)
#pragma unroll
        for (int n = 0; n < 4; ++n)
          acc[m][n] = __builtin_amdgcn_mfma_f32_16x16x32_bf16(aF[m], bF[n], acc[m][n], 0, 0, 0);
    }
    asm volatile("" ::: "memory");
  }
#undef STAGE
#pragma unroll
  for (int m = 0; m < 4; ++m)
#pragma unroll
    for (int n = 0; n < 4; ++n)
#pragma unroll
      for (int r = 0; r < 4; ++r) {
        int rr = row0 + wr + m * 16 + l4 * 4 + r;
        int cc = col0 + wc + n * 16 + l15;
        float v = acc[m][n][r];
        if (EPI == 1) {
          v += bias[cc];
          v = v / (1.f + __expf(-1.702f * v));
          ((unsigned short*)Cout)[(size_t)rr * N + cc] = f2bf(v);
        } else {
          v += bias[cc] + addsrc[(size_t)rr * N + cc];
          ((float*)Cout)[(size_t)rr * N + cc] = v;
        }
      }
}

// ---------------- flash-decode attention partials (swapped QK^T) --------
// Static-max softmax; Q pre-scaled by log2e/8 in gemm_fused, so
// p = exp2(S_scaled) directly — no per-score multiply.
__global__ __launch_bounds__(256, 4) void attn_partial(
    const unsigned short* __restrict__ Qb, const unsigned short* __restrict__ Kb,
    const unsigned short* __restrict__ Vt,
    unsigned short* __restrict__ Op, float* __restrict__ lp)
{
  __shared__ unsigned short Klds[2][64 * 64];
  __shared__ unsigned short Vlds[2][64 * 64];
  int tid = threadIdx.x, wid = tid >> 6, lane = tid & 63;
  int l15 = lane & 15, l4 = lane >> 4;
  int head = blockIdx.x >> 6, chunk = blockIdx.x & 63;
  int t0 = (49 * chunk) >> 3;
  int nkt = ((49 * (chunk + 1)) >> 3) - t0;   // 6 or 7

  short8 bQ[2][2];
#pragma unroll
  for (int m = 0; m < 2; ++m)
#pragma unroll
    for (int kk = 0; kk < 2; ++kk) {
      int qrow = wid * 32 + m * 16 + l15;
      bQ[m][kk] = *(const short8*)(Qb + (size_t)qrow * DIM + head * HD + kk * 32 + l4 * 8);
    }
  f32x4 accO[2][4] = {};
  float lrun[2] = { 0.f, 0.f };

  int srow = tid >> 3;                       // 0..31 within a 32-row pass
  int sblk = (tid & 7) ^ (srow & 7);
  const char* Kg = (const char*)(Kb + (size_t)(t0 * 64 + srow) * DIM + head * HD) + sblk * 16;
  const char* Vg = (const char*)(Vt + (size_t)(head * HD + srow) * ROWS_KV + t0 * 64) + sblk * 16;

#define STAGEKV(buf, kt) do {                                         \
    const char* k0 = Kg + (size_t)(kt) * 64 * DIM * 2;                \
    const char* v0 = Vg + (size_t)(kt) * 128;                         \
    char* lk = (char*)Klds[buf] + wid * 1024;                         \
    char* lv = (char*)Vlds[buf] + wid * 1024;                         \
    gload16(k0,                        lk);                           \
    gload16(k0 + (size_t)32 * DIM * 2, lk + 4096);                    \
    gload16(v0,                        lv);                           \
    gload16(v0 + (size_t)32 * ROWS_KV * 2, lv + 4096);                \
  } while (0)

  STAGEKV(0, 0);
  for (int kt = 0; kt < nkt; ++kt) {
    int cur = kt & 1;
    __builtin_amdgcn_s_barrier();   // all waves done reading buf[cur^1]
    asm volatile("" ::: "memory");
    if (kt + 1 < nkt) {
      STAGEKV(cur ^ 1, kt + 1);
      asm volatile("s_waitcnt vmcnt(4)" ::: "memory");
    } else {
      asm volatile("s_waitcnt vmcnt(0)" ::: "memory");
    }

    // S^T[key][q]: sc[n][m][r] = Ssc[q0+m*16+l15][key = n*16 + l4*4 + r]
    f32x4 sc[4][2] = {};
    __builtin_amdgcn_s_setprio(1);
#pragma unroll
    for (int kk = 0; kk < 2; ++kk) {
      short8 aK[4];
#pragma unroll
      for (int n = 0; n < 4; ++n) {
        int krow = n * 16 + l15;
        int blk = ((kk << 2) | l4) ^ (krow & 7);
        aK[n] = *(const short8*)((const char*)Klds[cur] + krow * 128 + blk * 16);
      }
#pragma unroll
      for (int n = 0; n < 4; ++n)
#pragma unroll
        for (int m = 0; m < 2; ++m)
          sc[n][m] = __builtin_amdgcn_mfma_f32_16x16x32_bf16(aK[n], bQ[m][kk], sc[n][m], 0, 0, 0);
    }
    __builtin_amdgcn_s_setprio(0);

    // static-max softmax: p = 2^(S_scaled); sum; pack bf16 via cvt_pk
    short8 pB[2][2];
#pragma unroll
    for (int m = 0; m < 2; ++m) {
      float rsum = 0.f;
#pragma unroll
      for (int n = 0; n < 4; ++n)
#pragma unroll
        for (int r = 0; r < 4; ++r) {
          float p;
          asm("v_exp_f32 %0, %1" : "=v"(p) : "v"(sc[n][m][r]));
          sc[n][m][r] = p;
          rsum += p;
        }
      rsum += __shfl_xor(rsum, 16);
      rsum += __shfl_xor(rsum, 32);
      lrun[m] += rsum;
#pragma unroll
      for (int kk2 = 0; kk2 < 2; ++kk2) {
        uint4v pw;
#pragma unroll
        for (int w = 0; w < 4; ++w) {
          int n = 2 * kk2 + (w >> 1);
          int r0 = (w & 1) * 2;
          unsigned int u;
          asm("v_cvt_pk_bf16_f32 %0, %1, %2"
              : "=v"(u) : "v"(sc[n][m][r0]), "v"(sc[n][m][r0 + 1]));
          pw[w] = u;
        }
        pB[m][kk2] = __builtin_bit_cast(short8, pw);
      }
    }

    // O^T += V'^T P'
    __builtin_amdgcn_s_setprio(1);
#pragma unroll
    for (int kk2 = 0; kk2 < 2; ++kk2) {
      short8 aV[4];
#pragma unroll
      for (int nb = 0; nb < 4; ++nb) {
        int row = nb * 16 + l15;
        int blk1 = (kk2 << 2) | (l4 >> 1);
        int in1 = (l4 & 1) << 3;
        const char* vb = (const char*)Vlds[cur] + row * 128;
        short4v lo = *(const short4v*)(vb + (((blk1 ^ (row & 7)) << 4) | in1));
        short4v hi = *(const short4v*)(vb + ((((blk1 + 2) ^ (row & 7)) << 4) | in1));
        aV[nb] = __builtin_shufflevector(lo, hi, 0, 1, 2, 3, 4, 5, 6, 7);
      }
#pragma unroll
      for (int m = 0; m < 2; ++m)
#pragma unroll
        for (int nb = 0; nb < 4; ++nb)
          accO[m][nb] = __builtin_amdgcn_mfma_f32_16x16x32_bf16(aV[nb], pB[m][kk2], accO[m][nb], 0, 0, 0);
    }
    __builtin_amdgcn_s_setprio(0);
    asm volatile("" ::: "memory");
  }
#undef STAGEKV
  size_t pb = (size_t)(head * NCHUNK + chunk) * 128;
#pragma unroll
  for (int m = 0; m < 2; ++m) {
    int q = wid * 32 + m * 16 + l15;
#pragma unroll
    for (int nb = 0; nb < 4; ++nb) {
      ushort4 o;
      o.x = f2bf(accO[m][nb][0]); o.y = f2bf(accO[m][nb][1]);
      o.z = f2bf(accO[m][nb][2]); o.w = f2bf(accO[m][nb][3]);
      *(ushort4*)(Op + (pb + q) * 64 + nb * 16 + l4 * 4) = o;
    }
    if (l4 == 0) {
      lp[pb + q] = lrun[m];
    }
  }
}

// ------- combine partials (plain sums; static max) + q1 + LN2 -> h -----
__device__ __forceinline__ float blk_sum256(float v, volatile float* red) {
  int tid = threadIdx.x;
#pragma unroll
  for (int o = 32; o; o >>= 1) v += __shfl_xor(v, o);
  __syncthreads();
  if ((tid & 63) == 0) red[tid >> 6] = v;
  __syncthreads();
  return red[0] + red[1] + red[2] + red[3];
}

__global__ __launch_bounds__(256) void combine_ln2(
    const unsigned short* __restrict__ Op, const float* __restrict__ lp,
    const float* __restrict__ q0f, const float* __restrict__ g2, const float* __restrict__ b2,
    float* __restrict__ q1, unsigned short* __restrict__ hb)
{
  int q = blockIdx.x, tid = threadIdx.x;
  __shared__ float lS[HEADS * NCHUNK];
  __shared__ float red[4];
  for (int i = tid; i < HEADS * NCHUNK; i += 256)
    lS[i] = lp[(size_t)i * 128 + q];
  __syncthreads();
  float vals[3];
#pragma unroll
  for (int ii = 0; ii < 3; ++ii) {
    int c = tid + ii * 256;
    int h = c >> 6, d = c & 63;
    float num = 0.f, den = 0.f;
    for (int cc = 0; cc < NCHUNK; ++cc) {
      den += lS[h * NCHUNK + cc];
      num += bf2f(Op[((size_t)(h * NCHUNK + cc) * 128 + q) * 64 + d]);
    }
    float ctx = 0.5f * num / den;
    float v = q0f[(size_t)q * DIM + c] + ctx;
    q1[(size_t)q * DIM + c] = v;
    vals[ii] = v;
  }
  float s = blk_sum256(vals[0] + vals[1] + vals[2], red);
  float mean = s * (1.f / 768.f);
  float d0 = vals[0] - mean, d1 = vals[1] - mean, d2 = vals[2] - mean;
  float ss = blk_sum256(d0 * d0 + d1 * d1 + d2 * d2, red);
  float rs = rsqrtf(ss * (1.f / 768.f) + 1e-5f);
#pragma unroll
  for (int ii = 0; ii < 3; ++ii) {
    int c = tid + ii * 256;
    hb[(size_t)q * DIM + c] = f2bf((vals[ii] - mean) * rs * g2[c] + b2[c]);
  }
}

// ------------------------------- host -----------------------------------
extern "C" void kernel_launch(void* const* d_in, const int* in_sizes, int n_in,
                              void* d_out, int out_size, void* d_ws, size_t ws_size,
                              hipStream_t stream) {
  const float* x   = (const float*)d_in[0];
  const float* cls = (const float*)d_in[1];
  const float* g1  = (const float*)d_in[2];
  const float* b1  = (const float*)d_in[3];
  const float* g2  = (const float*)d_in[4];
  const float* b2  = (const float*)d_in[5];
  const float* Wq  = (const float*)d_in[6];
  const float* Wk  = (const float*)d_in[7];
  const float* Wv  = (const float*)d_in[8];
  const float* fcw = (const float*)d_in[13];
  const float* fcb = (const float*)d_in[14];
  const float* pw  = (const float*)d_in[15];
  const float* pb  = (const float*)d_in[16];

  char* ws = (char*)d_ws;
  size_t off = 0;
  auto alloc = [&](size_t bytes) {
    char* p = ws + off;
    off += (bytes + 255) & ~(size_t)255;
    return p;
  };
  unsigned char*  xx8  = (unsigned char*)alloc((size_t)ROWS_ALL * DIM);
  float*          q0f  = (float*)alloc((size_t)NB * DIM * 4);
  unsigned short* Kbf  = (unsigned short*)alloc((size_t)ROWS_KV * DIM * 2);
  unsigned short* Vtb  = (unsigned short*)alloc((size_t)DIM * ROWS_KV * 2);
  unsigned short* Qbf  = (unsigned short*)alloc((size_t)NB * DIM * 2);
  unsigned char*  w8   = (unsigned char*)alloc((size_t)3 * DIM * DIM);
  unsigned short* wbf  = (unsigned short*)alloc((size_t)2 * DIM * DIM * 2);
  unsigned short* Opar = (unsigned short*)alloc((size_t)HEADS * NCHUNK * 128 * 64 * 2);
  float*          lpar = (float*)alloc((size_t)HEADS * NCHUNK * 128 * 4);
  float*          q1   = (float*)alloc((size_t)NB * DIM * 4);
  unsigned short* hb   = (unsigned short*)alloc((size_t)NB * DIM * 2);
  unsigned short* m1b  = (unsigned short*)alloc((size_t)NB * DIM * 2);

  unsigned char* Wq8 = w8;
  unsigned char* Wk8 = w8 + (size_t)1 * DIM * DIM;
  unsigned char* Wv8 = w8 + (size_t)2 * DIM * DIM;
  unsigned short* fwb = wbf;
  unsigned short* pwb = wbf + (size_t)1 * DIM * DIM;

  // fused LN1 + weight casts (6304 LN blocks + 2880 cast blocks)
  ln1_cast<<<ROWS_ALL / 4 + 2880, 256, 0, stream>>>(
      x, cls, g1, b1, xx8, q0f, Wq, Wk, Wv, fcw, pw, w8, wbf);

  // fused K / V^T / Q projections (2358 blocks, fp8 inputs)
  gemm_fused<<<1176 + 1176 + 6, 256, 0, stream>>>(
      xx8 + (size_t)NB * DIM, Wk8, Kbf, Wv8, Vtb, xx8, Wq8, Qbf);

  attn_partial<<<HEADS * NCHUNK, 256, 0, stream>>>(Qbf, Kbf, Vtb, Opar, lpar);
  combine_ln2<<<NB, 256, 0, stream>>>(Opar, lpar, q0f, g2, b2, q1, hb);

  // m1 = silu(h @ fc_w^T + fc_b)
  gemm_bt64<1><<<dim3(DIM / 128, 1), 256, 0, stream>>>(
      hb, fwb, m1b, NB, DIM, DIM, fcb, nullptr);
  // out = q1 + m1 @ proj_w^T + proj_b
  gemm_bt64<2><<<dim3(DIM / 128, 1), 256, 0, stream>>>(
      m1b, pwb, d_out, NB, DIM, DIM, pb, q1);
}

// Round 15
// 136.692 us; speedup vs baseline: 2.9321x; 1.0121x over previous
//
#include <hip/hip_runtime.h>

#define DIM 768
#define HEADS 12
#define HD 64
#define NB 128
#define ROWS_ALL 25216   // 197*128
#define ROWS_KV  25088   // 196*128
#define NCHUNK 64        // chunks per head; chunk c covers key-tiles [49c/8, 49(c+1)/8)

typedef __attribute__((ext_vector_type(8))) short short8;
typedef __attribute__((ext_vector_type(4))) short short4v;
typedef __attribute__((ext_vector_type(4))) float f32x4;
typedef __attribute__((ext_vector_type(4))) unsigned int uint4v;
typedef long long i64;
typedef __attribute__((ext_vector_type(2))) long long i64x2;

__device__ __forceinline__ unsigned short f2bf(float f) {
  union { float f; unsigned u; } a; a.f = f;
  return (unsigned short)((a.u + 0x7fffu + ((a.u >> 16) & 1u)) >> 16);
}
__device__ __forceinline__ float bf2f(unsigned short u) {
  union { unsigned u; float f; } a; a.u = ((unsigned)u) << 16;
  return a.f;
}
// pack 4 f32 -> 4 fp8 e4m3 (OCP on gfx950)
__device__ __forceinline__ unsigned pk_fp8x4(float a, float b, float c, float d) {
  int p = __builtin_amdgcn_cvt_pk_fp8_f32(a, b, 0, false);
  p = __builtin_amdgcn_cvt_pk_fp8_f32(c, d, p, true);
  return (unsigned)p;
}

__device__ __forceinline__ void gload16(const void* g, void* l) {
  __builtin_amdgcn_global_load_lds(
      (__attribute__((address_space(1))) void*)g,
      (__attribute__((address_space(3))) void*)l, 16, 0, 0);
}

// ------ fused: LN1 -> fp8 xx + f32 q0; cast Wq/Wk/Wv->fp8, fcw/pw->bf16 --
__global__ __launch_bounds__(256) void ln1_cast(
    const float* __restrict__ x, const float* __restrict__ cls,
    const float* __restrict__ g, const float* __restrict__ b,
    unsigned char* __restrict__ xx8, float* __restrict__ q0f,
    const float* __restrict__ Wq, const float* __restrict__ Wk,
    const float* __restrict__ Wv, const float* __restrict__ fcw,
    const float* __restrict__ pw,
    unsigned char* __restrict__ w8, unsigned short* __restrict__ wbf)
{
  int blk = blockIdx.x, tid = threadIdx.x;
  if (blk < ROWS_ALL / 4) {
    int row = blk * 4 + (tid >> 6);
    int lane = tid & 63;
    const float* src = (row < NB) ? (cls + (size_t)row * DIM)
                                  : (x + (size_t)(row - NB) * DIM);
    float4 v[3];
    float s = 0.f;
#pragma unroll
    for (int i = 0; i < 3; ++i) {
      v[i] = ((const float4*)src)[lane + 64 * i];
      s += v[i].x + v[i].y + v[i].z + v[i].w;
    }
#pragma unroll
    for (int o = 32; o; o >>= 1) s += __shfl_xor(s, o);
    float mean = s * (1.f / 768.f);
    float ss = 0.f;
#pragma unroll
    for (int i = 0; i < 3; ++i) {
      float a0 = v[i].x - mean, a1 = v[i].y - mean, a2 = v[i].z - mean, a3 = v[i].w - mean;
      ss += a0 * a0 + a1 * a1 + a2 * a2 + a3 * a3;
    }
#pragma unroll
    for (int o = 32; o; o >>= 1) ss += __shfl_xor(ss, o);
    float rs = rsqrtf(ss * (1.f / 768.f) + 1e-5f);
#pragma unroll
    for (int i = 0; i < 3; ++i) {
      int c4 = lane + 64 * i;
      float4 gv = ((const float4*)g)[c4];
      float4 bv = ((const float4*)b)[c4];
      float o0 = (v[i].x - mean) * rs * gv.x + bv.x;
      float o1 = (v[i].y - mean) * rs * gv.y + bv.y;
      float o2 = (v[i].z - mean) * rs * gv.z + bv.z;
      float o3 = (v[i].w - mean) * rs * gv.w + bv.w;
      ((unsigned*)(xx8 + (size_t)row * DIM))[c4] = pk_fp8x4(o0, o1, o2, o3);
      if (row < NB) {
        float4 fo; fo.x = o0; fo.y = o1; fo.z = o2; fo.w = o3;
        ((float4*)(q0f + (size_t)row * DIM))[c4] = fo;
      }
    }
  } else {
    int idx = blk - ROWS_ALL / 4;          // [0, 2880)
    int w = idx / 576;                     // matrix id, uniform per block
    int j4 = (idx % 576) * 256 + tid;      // float4 index within matrix
    const float* s = (w == 0) ? Wq : (w == 1) ? Wk : (w == 2) ? Wv
                   : (w == 3) ? fcw : pw;
    float4 v = ((const float4*)s)[j4];
    if (w < 3) {
      ((unsigned*)(w8 + (size_t)w * (DIM * DIM)))[j4] = pk_fp8x4(v.x, v.y, v.z, v.w);
    } else {
      ushort4 u; u.x = f2bf(v.x); u.y = f2bf(v.y); u.z = f2bf(v.z); u.w = f2bf(v.w);
      ((ushort4*)(wbf + (size_t)(w - 3) * (DIM * DIM)))[j4] = u;
    }
  }
}

// ======= fused QKV projection GEMMs: 128x128 tile, FP8 inputs, BK=64 ====
// 12 K-steps (fp8 halves bytes/K). Fragment reads are single ds_read_b128
// per (frag, kk-pair): the contraction index is RELABELED so lane l4 holds
// original k-bytes [16*l4, +8) for kk=0 and [16*l4+8, +8) for kk=1 — legal
// since A and B use the same relabeling. This reproduces the bf16 kernel's
// measured zero-conflict pattern (round-14's b64 reads hit only even banks:
// 7.24M conflicts). Outputs bf16 (Q pre-scaled by log2e/8 for attn's exp2).
__global__ __launch_bounds__(256, 4) void gemm_fused(
    const unsigned char* __restrict__ xxkv, const unsigned char* __restrict__ Wk8,
    unsigned short* __restrict__ Kbf,
    const unsigned char* __restrict__ Wv8, unsigned short* __restrict__ Vtb,
    const unsigned char* __restrict__ xxall, const unsigned char* __restrict__ Wq8,
    unsigned short* __restrict__ Qbf)
{
  __shared__ unsigned char Asm[128 * 64];   // 8KB
  __shared__ unsigned char Bsm[128 * 64];   // 8KB
  int tid = threadIdx.x, wid = tid >> 6, lane = tid & 63;
  int l15 = lane & 15, l4 = lane >> 4;

  int nwg = gridDim.x;
  int bid = blockIdx.x;
  int q8 = nwg >> 3, r8 = nwg & 7;
  int xcd = bid & 7, rank = bid >> 3;
  int swz = (xcd < r8 ? xcd * (q8 + 1) : r8 * (q8 + 1) + (xcd - r8) * q8) + rank;

  const unsigned char *A, *Bt;
  unsigned short* C;
  int N, row0, col0;
  const int K = DIM;                 // 768 fp8 bytes per row
  if (swz < 1176) {                  // K = xx_kv @ Wk^T
    A = xxkv; Bt = Wk8; C = Kbf; N = DIM;
    row0 = (swz / 6) * 128; col0 = (swz % 6) * 128;
  } else if (swz < 2352) {           // V^T = Wv @ xx_kv^T
    int inner = swz - 1176;
    A = Wv8; Bt = xxkv; C = Vtb; N = ROWS_KV;
    row0 = (inner % 6) * 128; col0 = (inner / 6) * 128;
  } else {                           // Q = xx_cls @ Wq^T (pre-scaled)
    int inner = swz - 2352;
    A = xxall; Bt = Wq8; C = Qbf; N = DIM;
    row0 = 0; col0 = inner * 128;
  }
  float csc = (swz >= 2352) ? 0.18033688011112042f : 1.0f;  // log2e/8 for Q

  int srow = tid >> 2;
  int sq = tid & 3;
  int sb = sq ^ ((srow >> 1) & 3);
  const unsigned char* Ag = A + (size_t)(row0 + srow) * K + sb * 16;
  const unsigned char* Bg = Bt + (size_t)(col0 + srow) * K + sb * 16;
  size_t rstep64 = (size_t)64 * K;

  f32x4 acc[4][4] = {};
  int wr = (wid >> 1) * 64, wc = (wid & 1) * 64;
  const int nk = K >> 6;             // 12 K-steps of BK=64 (64 bytes/row)
  for (int t = 0; t < nk; ++t) {
    {
      const unsigned char* a0 = Ag + (size_t)t * 64;
      const unsigned char* b0 = Bg + (size_t)t * 64;
      char* la = (char*)Asm + wid * 1024;
      char* lb = (char*)Bsm + wid * 1024;
      gload16(a0,           la);
      gload16(a0 + rstep64, la + 4096);
      gload16(b0,           lb);
      gload16(b0 + rstep64, lb + 4096);
    }
    asm volatile("s_waitcnt vmcnt(0)" ::: "memory");
    __builtin_amdgcn_s_barrier();
    asm volatile("" ::: "memory");
    i64x2 aF[4], bF[4];
#pragma unroll
    for (int m = 0; m < 4; ++m) {
      int row = wr + m * 16 + l15;
      aF[m] = *(const i64x2*)((const char*)Asm + row * 64 + ((l4 ^ ((row >> 1) & 3)) << 4));
    }
#pragma unroll
    for (int n = 0; n < 4; ++n) {
      int row = wc + n * 16 + l15;
      bF[n] = *(const i64x2*)((const char*)Bsm + row * 64 + ((l4 ^ ((row >> 1) & 3)) << 4));
    }
    __builtin_amdgcn_s_setprio(1);
#pragma unroll
    for (int kk = 0; kk < 2; ++kk)
#pragma unroll
      for (int m = 0; m < 4; ++m)
#pragma unroll
        for (int n = 0; n < 4; ++n)
          acc[m][n] = __builtin_amdgcn_mfma_f32_16x16x32_fp8_fp8(
              aF[m][kk], bF[n][kk], acc[m][n], 0, 0, 0);
    __builtin_amdgcn_s_setprio(0);
    asm volatile("" ::: "memory");
    __builtin_amdgcn_s_barrier();
    asm volatile("" ::: "memory");
  }
#pragma unroll
  for (int m = 0; m < 4; ++m)
#pragma unroll
    for (int n = 0; n < 4; ++n)
#pragma unroll
      for (int r = 0; r < 4; ++r) {
        int rr = row0 + wr + m * 16 + l4 * 4 + r;
        int cc = col0 + wc + n * 16 + l15;
        C[(size_t)rr * N + cc] = f2bf(acc[m][n][r] * csc);
      }
}

// ======= 128x128 tile GEMM (small M epilogue cases), BK=64, 1 barrier ===
// EPI 1: +bias, silu(1.702), bf16 store; 2: +bias +addsrc, f32 store
template <int EPI>
__global__ __launch_bounds__(256, 2) void gemm_bt64(
    const unsigned short* __restrict__ A, const unsigned short* __restrict__ Bt,
    void* __restrict__ Cout, int M, int N, int K,
    const float* __restrict__ bias, const float* __restrict__ addsrc)
{
  __shared__ unsigned short Asm[2][128 * 64];
  __shared__ unsigned short Bsm[2][128 * 64];
  int tid = threadIdx.x, wid = tid >> 6, lane = tid & 63;
  int l15 = lane & 15, l4 = lane >> 4;
  int row0 = blockIdx.y * 128, col0 = blockIdx.x * 128;

  int srow = tid >> 3;
  int scol = ((tid & 7) ^ (srow & 7)) << 4;
  const char* Ag = (const char*)A + (size_t)(row0 + srow) * K * 2 + scol;
  const char* Bg = (const char*)Bt + (size_t)(col0 + srow) * K * 2 + scol;
  size_t rstep32 = (size_t)32 * K * 2;

#define STAGE(buf, kt) do {                                           \
    const char* a0 = Ag + (size_t)(kt) * 128;                         \
    const char* b0 = Bg + (size_t)(kt) * 128;                         \
    char* la = (char*)Asm[buf] + wid * 1024;                          \
    char* lb = (char*)Bsm[buf] + wid * 1024;                          \
    gload16(a0,                la);                                   \
    gload16(a0 + rstep32,      la + 4096);                            \
    gload16(a0 + 2 * rstep32,  la + 8192);                            \
    gload16(a0 + 3 * rstep32,  la + 12288);                           \
    gload16(b0,                lb);                                   \
    gload16(b0 + rstep32,      lb + 4096);                            \
    gload16(b0 + 2 * rstep32,  lb + 8192);                            \
    gload16(b0 + 3 * rstep32,  lb + 12288);                           \
  } while (0)

  f32x4 acc[4][4] = {};
  int wr = (wid >> 1) * 64, wc = (wid & 1) * 64;
  int nk = K >> 6;                 // BK=64
  STAGE(0, 0);
  for (int t = 0; t < nk; ++t) {
    int cur = t & 1;
    __builtin_amdgcn_s_barrier();
    asm volatile("" ::: "memory");
    if (t + 1 < nk) {
      STAGE(cur ^ 1, t + 1);
      asm volatile("s_waitcnt vmcnt(8)" ::: "memory");
    } else {
      asm volatile("s_waitcnt vmcnt(0)" ::: "memory");
    }
    const char* Ab = (const char*)Asm[cur];
    const char* Bb = (const char*)Bsm[cur];
#pragma unroll
    for (int kk = 0; kk < 2; ++kk) {
      short8 aF[4], bF[4];
#pragma unroll
      for (int m = 0; m < 4; ++m) {
        int row = wr + m * 16 + l15;
        aF[m] = *(const short8*)(Ab + row * 128 + ((((kk << 2) | l4) ^ (row & 7)) << 4));
      }
#pragma unroll
      for (int n = 0; n < 4; ++n) {
        int row = wc + n * 16 + l15;
        bF[n] = *(const short8*)(Bb + row * 128 + ((((kk << 2) | l4) ^ (row & 7)) << 4));
      }
#pragma unroll
      for (int m = 0; m < 4; ++m)
#pragma unroll
        for (int n = 0; n < 4; ++n)
          acc[m][n] = __builtin_amdgcn_mfma_f32_16x16x32_bf16(aF[m], bF[n], acc[m][n], 0, 0, 0);
    }
    asm volatile("" ::: "memory");
  }
#undef STAGE
#pragma unroll
  for (int m = 0; m < 4; ++m)
#pragma unroll
    for (int n = 0; n < 4; ++n)
#pragma unroll
      for (int r = 0; r < 4; ++r) {
        int rr = row0 + wr + m * 16 + l4 * 4 + r;
        int cc = col0 + wc + n * 16 + l15;
        float v = acc[m][n][r];
        if (EPI == 1) {
          v += bias[cc];
          v = v / (1.f + __expf(-1.702f * v));
          ((unsigned short*)Cout)[(size_t)rr * N + cc] = f2bf(v);
        } else {
          v += bias[cc] + addsrc[(size_t)rr * N + cc];
          ((float*)Cout)[(size_t)rr * N + cc] = v;
        }
      }
}

// ---------------- flash-decode attention partials (swapped QK^T) --------
// Static-max softmax; Q pre-scaled by log2e/8 in gemm_fused, so
// p = exp2(S_scaled) directly — no per-score multiply.
__global__ __launch_bounds__(256, 4) void attn_partial(
    const unsigned short* __restrict__ Qb, const unsigned short* __restrict__ Kb,
    const unsigned short* __restrict__ Vt,
    unsigned short* __restrict__ Op, float* __restrict__ lp)
{
  __shared__ unsigned short Klds[2][64 * 64];
  __shared__ unsigned short Vlds[2][64 * 64];
  int tid = threadIdx.x, wid = tid >> 6, lane = tid & 63;
  int l15 = lane & 15, l4 = lane >> 4;
  int head = blockIdx.x >> 6, chunk = blockIdx.x & 63;
  int t0 = (49 * chunk) >> 3;
  int nkt = ((49 * (chunk + 1)) >> 3) - t0;   // 6 or 7

  short8 bQ[2][2];
#pragma unroll
  for (int m = 0; m < 2; ++m)
#pragma unroll
    for (int kk = 0; kk < 2; ++kk) {
      int qrow = wid * 32 + m * 16 + l15;
      bQ[m][kk] = *(const short8*)(Qb + (size_t)qrow * DIM + head * HD + kk * 32 + l4 * 8);
    }
  f32x4 accO[2][4] = {};
  float lrun[2] = { 0.f, 0.f };

  int srow = tid >> 3;                       // 0..31 within a 32-row pass
  int sblk = (tid & 7) ^ (srow & 7);
  const char* Kg = (const char*)(Kb + (size_t)(t0 * 64 + srow) * DIM + head * HD) + sblk * 16;
  const char* Vg = (const char*)(Vt + (size_t)(head * HD + srow) * ROWS_KV + t0 * 64) + sblk * 16;

#define STAGEKV(buf, kt) do {                                         \
    const char* k0 = Kg + (size_t)(kt) * 64 * DIM * 2;                \
    const char* v0 = Vg + (size_t)(kt) * 128;                         \
    char* lk = (char*)Klds[buf] + wid * 1024;                         \
    char* lv = (char*)Vlds[buf] + wid * 1024;                         \
    gload16(k0,                        lk);                           \
    gload16(k0 + (size_t)32 * DIM * 2, lk + 4096);                    \
    gload16(v0,                        lv);                           \
    gload16(v0 + (size_t)32 * ROWS_KV * 2, lv + 4096);                \
  } while (0)

  STAGEKV(0, 0);
  for (int kt = 0; kt < nkt; ++kt) {
    int cur = kt & 1;
    __builtin_amdgcn_s_barrier();   // all waves done reading buf[cur^1]
    asm volatile("" ::: "memory");
    if (kt + 1 < nkt) {
      STAGEKV(cur ^ 1, kt + 1);
      asm volatile("s_waitcnt vmcnt(4)" ::: "memory");
    } else {
      asm volatile("s_waitcnt vmcnt(0)" ::: "memory");
    }

    // S^T[key][q]: sc[n][m][r] = Ssc[q0+m*16+l15][key = n*16 + l4*4 + r]
    f32x4 sc[4][2] = {};
    __builtin_amdgcn_s_setprio(1);
#pragma unroll
    for (int kk = 0; kk < 2; ++kk) {
      short8 aK[4];
#pragma unroll
      for (int n = 0; n < 4; ++n) {
        int krow = n * 16 + l15;
        int blk = ((kk << 2) | l4) ^ (krow & 7);
        aK[n] = *(const short8*)((const char*)Klds[cur] + krow * 128 + blk * 16);
      }
#pragma unroll
      for (int n = 0; n < 4; ++n)
#pragma unroll
        for (int m = 0; m < 2; ++m)
          sc[n][m] = __builtin_amdgcn_mfma_f32_16x16x32_bf16(aK[n], bQ[m][kk], sc[n][m], 0, 0, 0);
    }
    __builtin_amdgcn_s_setprio(0);

    // static-max softmax: p = 2^(S_scaled); sum; pack bf16 via cvt_pk
    short8 pB[2][2];
#pragma unroll
    for (int m = 0; m < 2; ++m) {
      float rsum = 0.f;
#pragma unroll
      for (int n = 0; n < 4; ++n)
#pragma unroll
        for (int r = 0; r < 4; ++r) {
          float p;
          asm("v_exp_f32 %0, %1" : "=v"(p) : "v"(sc[n][m][r]));
          sc[n][m][r] = p;
          rsum += p;
        }
      rsum += __shfl_xor(rsum, 16);
      rsum += __shfl_xor(rsum, 32);
      lrun[m] += rsum;
#pragma unroll
      for (int kk2 = 0; kk2 < 2; ++kk2) {
        uint4v pw;
#pragma unroll
        for (int w = 0; w < 4; ++w) {
          int n = 2 * kk2 + (w >> 1);
          int r0 = (w & 1) * 2;
          unsigned int u;
          asm("v_cvt_pk_bf16_f32 %0, %1, %2"
              : "=v"(u) : "v"(sc[n][m][r0]), "v"(sc[n][m][r0 + 1]));
          pw[w] = u;
        }
        pB[m][kk2] = __builtin_bit_cast(short8, pw);
      }
    }

    // O^T += V'^T P'
    __builtin_amdgcn_s_setprio(1);
#pragma unroll
    for (int kk2 = 0; kk2 < 2; ++kk2) {
      short8 aV[4];
#pragma unroll
      for (int nb = 0; nb < 4; ++nb) {
        int row = nb * 16 + l15;
        int blk1 = (kk2 << 2) | (l4 >> 1);
        int in1 = (l4 & 1) << 3;
        const char* vb = (const char*)Vlds[cur] + row * 128;
        short4v lo = *(const short4v*)(vb + (((blk1 ^ (row & 7)) << 4) | in1));
        short4v hi = *(const short4v*)(vb + ((((blk1 + 2) ^ (row & 7)) << 4) | in1));
        aV[nb] = __builtin_shufflevector(lo, hi, 0, 1, 2, 3, 4, 5, 6, 7);
      }
#pragma unroll
      for (int m = 0; m < 2; ++m)
#pragma unroll
        for (int nb = 0; nb < 4; ++nb)
          accO[m][nb] = __builtin_amdgcn_mfma_f32_16x16x32_bf16(aV[nb], pB[m][kk2], accO[m][nb], 0, 0, 0);
    }
    __builtin_amdgcn_s_setprio(0);
    asm volatile("" ::: "memory");
  }
#undef STAGEKV
  size_t pb = (size_t)(head * NCHUNK + chunk) * 128;
#pragma unroll
  for (int m = 0; m < 2; ++m) {
    int q = wid * 32 + m * 16 + l15;
#pragma unroll
    for (int nb = 0; nb < 4; ++nb) {
      ushort4 o;
      o.x = f2bf(accO[m][nb][0]); o.y = f2bf(accO[m][nb][1]);
      o.z = f2bf(accO[m][nb][2]); o.w = f2bf(accO[m][nb][3]);
      *(ushort4*)(Op + (pb + q) * 64 + nb * 16 + l4 * 4) = o;
    }
    if (l4 == 0) {
      lp[pb + q] = lrun[m];
    }
  }
}

// ------- combine partials (plain sums; static max) + q1 + LN2 -> h -----
__device__ __forceinline__ float blk_sum256(float v, volatile float* red) {
  int tid = threadIdx.x;
#pragma unroll
  for (int o = 32; o; o >>= 1) v += __shfl_xor(v, o);
  __syncthreads();
  if ((tid & 63) == 0) red[tid >> 6] = v;
  __syncthreads();
  return red[0] + red[1] + red[2] + red[3];
}

__global__ __launch_bounds__(256) void combine_ln2(
    const unsigned short* __restrict__ Op, const float* __restrict__ lp,
    const float* __restrict__ q0f, const float* __restrict__ g2, const float* __restrict__ b2,
    float* __restrict__ q1, unsigned short* __restrict__ hb)
{
  int q = blockIdx.x, tid = threadIdx.x;
  __shared__ float lS[HEADS * NCHUNK];
  __shared__ float red[4];
  for (int i = tid; i < HEADS * NCHUNK; i += 256)
    lS[i] = lp[(size_t)i * 128 + q];
  __syncthreads();
  float vals[3];
#pragma unroll
  for (int ii = 0; ii < 3; ++ii) {
    int c = tid + ii * 256;
    int h = c >> 6, d = c & 63;
    float num = 0.f, den = 0.f;
    for (int cc = 0; cc < NCHUNK; ++cc) {
      den += lS[h * NCHUNK + cc];
      num += bf2f(Op[((size_t)(h * NCHUNK + cc) * 128 + q) * 64 + d]);
    }
    float ctx = 0.5f * num / den;
    float v = q0f[(size_t)q * DIM + c] + ctx;
    q1[(size_t)q * DIM + c] = v;
    vals[ii] = v;
  }
  float s = blk_sum256(vals[0] + vals[1] + vals[2], red);
  float mean = s * (1.f / 768.f);
  float d0 = vals[0] - mean, d1 = vals[1] - mean, d2 = vals[2] - mean;
  float ss = blk_sum256(d0 * d0 + d1 * d1 + d2 * d2, red);
  float rs = rsqrtf(ss * (1.f / 768.f) + 1e-5f);
#pragma unroll
  for (int ii = 0; ii < 3; ++ii) {
    int c = tid + ii * 256;
    hb[(size_t)q * DIM + c] = f2bf((vals[ii] - mean) * rs * g2[c] + b2[c]);
  }
}

// ------------------------------- host -----------------------------------
extern "C" void kernel_launch(void* const* d_in, const int* in_sizes, int n_in,
                              void* d_out, int out_size, void* d_ws, size_t ws_size,
                              hipStream_t stream) {
  const float* x   = (const float*)d_in[0];
  const float* cls = (const float*)d_in[1];
  const float* g1  = (const float*)d_in[2];
  const float* b1  = (const float*)d_in[3];
  const float* g2  = (const float*)d_in[4];
  const float* b2  = (const float*)d_in[5];
  const float* Wq  = (const float*)d_in[6];
  const float* Wk  = (const float*)d_in[7];
  const float* Wv  = (const float*)d_in[8];
  const float* fcw = (const float*)d_in[13];
  const float* fcb = (const float*)d_in[14];
  const float* pw  = (const float*)d_in[15];
  const float* pb  = (const float*)d_in[16];

  char* ws = (char*)d_ws;
  size_t off = 0;
  auto alloc = [&](size_t bytes) {
    char* p = ws + off;
    off += (bytes + 255) & ~(size_t)255;
    return p;
  };
  unsigned char*  xx8  = (unsigned char*)alloc((size_t)ROWS_ALL * DIM);
  float*          q0f  = (float*)alloc((size_t)NB * DIM * 4);
  unsigned short* Kbf  = (unsigned short*)alloc((size_t)ROWS_KV * DIM * 2);
  unsigned short* Vtb  = (unsigned short*)alloc((size_t)DIM * ROWS_KV * 2);
  unsigned short* Qbf  = (unsigned short*)alloc((size_t)NB * DIM * 2);
  unsigned char*  w8   = (unsigned char*)alloc((size_t)3 * DIM * DIM);
  unsigned short* wbf  = (unsigned short*)alloc((size_t)2 * DIM * DIM * 2);
  unsigned short* Opar = (unsigned short*)alloc((size_t)HEADS * NCHUNK * 128 * 64 * 2);
  float*          lpar = (float*)alloc((size_t)HEADS * NCHUNK * 128 * 4);
  float*          q1   = (float*)alloc((size_t)NB * DIM * 4);
  unsigned short* hb   = (unsigned short*)alloc((size_t)NB * DIM * 2);
  unsigned short* m1b  = (unsigned short*)alloc((size_t)NB * DIM * 2);

  unsigned char* Wq8 = w8;
  unsigned char* Wk8 = w8 + (size_t)1 * DIM * DIM;
  unsigned char* Wv8 = w8 + (size_t)2 * DIM * DIM;
  unsigned short* fwb = wbf;
  unsigned short* pwb = wbf + (size_t)1 * DIM * DIM;

  // fused LN1 + weight casts (6304 LN blocks + 2880 cast blocks)
  ln1_cast<<<ROWS_ALL / 4 + 2880, 256, 0, stream>>>(
      x, cls, g1, b1, xx8, q0f, Wq, Wk, Wv, fcw, pw, w8, wbf);

  // fused K / V^T / Q projections (2358 blocks, fp8 inputs)
  gemm_fused<<<1176 + 1176 + 6, 256, 0, stream>>>(
      xx8 + (size_t)NB * DIM, Wk8, Kbf, Wv8, Vtb, xx8, Wq8, Qbf);

  attn_partial<<<HEADS * NCHUNK, 256, 0, stream>>>(Qbf, Kbf, Vtb, Opar, lpar);
  combine_ln2<<<NB, 256, 0, stream>>>(Opar, lpar, q0f, g2, b2, q1, hb);

  // m1 = silu(h @ fc_w^T + fc_b)
  gemm_bt64<1><<<dim3(DIM / 128, 1), 256, 0, stream>>>(
      hb, fwb, m1b, NB, DIM, DIM, fcb, nullptr);
  // out = q1 + m1 @ proj_w^T + proj_b
  gemm_bt64<2><<<dim3(DIM / 128, 1), 256, 0, stream>>>(
      m1b, pwb, d_out, NB, DIM, DIM, pb, q1);
}

// Round 16
// 132.341 us; speedup vs baseline: 3.0285x; 1.0329x over previous
//
#include <hip/hip_runtime.h>

#define DIM 768
#define HEADS 12
#define HD 64
#define NB 128
#define ROWS_ALL 25216   // 197*128
#define ROWS_KV  25088   // 196*128
#define NCHUNK 64        // chunks per head; chunk c covers key-tiles [49c/8, 49(c+1)/8)

typedef __attribute__((ext_vector_type(8))) short short8;
typedef __attribute__((ext_vector_type(4))) short short4v;
typedef __attribute__((ext_vector_type(4))) float f32x4;
typedef __attribute__((ext_vector_type(4))) unsigned int uint4v;
typedef long long i64;
typedef __attribute__((ext_vector_type(2))) long long i64x2;

__device__ __forceinline__ unsigned short f2bf(float f) {
  union { float f; unsigned u; } a; a.f = f;
  return (unsigned short)((a.u + 0x7fffu + ((a.u >> 16) & 1u)) >> 16);
}
__device__ __forceinline__ float bf2f(unsigned short u) {
  union { unsigned u; float f; } a; a.u = ((unsigned)u) << 16;
  return a.f;
}
// pack 4 f32 -> 4 fp8 e4m3 (OCP on gfx950)
__device__ __forceinline__ unsigned pk_fp8x4(float a, float b, float c, float d) {
  int p = __builtin_amdgcn_cvt_pk_fp8_f32(a, b, 0, false);
  p = __builtin_amdgcn_cvt_pk_fp8_f32(c, d, p, true);
  return (unsigned)p;
}

__device__ __forceinline__ void gload16(const void* g, void* l) {
  __builtin_amdgcn_global_load_lds(
      (__attribute__((address_space(1))) void*)g,
      (__attribute__((address_space(3))) void*)l, 16, 0, 0);
}

// ------ fused: LN1 -> fp8 xx + f32 q0; cast Wq/Wk/Wv->fp8, fcw/pw->bf16 --
__global__ __launch_bounds__(256) void ln1_cast(
    const float* __restrict__ x, const float* __restrict__ cls,
    const float* __restrict__ g, const float* __restrict__ b,
    unsigned char* __restrict__ xx8, float* __restrict__ q0f,
    const float* __restrict__ Wq, const float* __restrict__ Wk,
    const float* __restrict__ Wv, const float* __restrict__ fcw,
    const float* __restrict__ pw,
    unsigned char* __restrict__ w8, unsigned short* __restrict__ wbf)
{
  int blk = blockIdx.x, tid = threadIdx.x;
  if (blk < ROWS_ALL / 4) {
    int row = blk * 4 + (tid >> 6);
    int lane = tid & 63;
    const float* src = (row < NB) ? (cls + (size_t)row * DIM)
                                  : (x + (size_t)(row - NB) * DIM);
    float4 v[3];
    float s = 0.f;
#pragma unroll
    for (int i = 0; i < 3; ++i) {
      v[i] = ((const float4*)src)[lane + 64 * i];
      s += v[i].x + v[i].y + v[i].z + v[i].w;
    }
#pragma unroll
    for (int o = 32; o; o >>= 1) s += __shfl_xor(s, o);
    float mean = s * (1.f / 768.f);
    float ss = 0.f;
#pragma unroll
    for (int i = 0; i < 3; ++i) {
      float a0 = v[i].x - mean, a1 = v[i].y - mean, a2 = v[i].z - mean, a3 = v[i].w - mean;
      ss += a0 * a0 + a1 * a1 + a2 * a2 + a3 * a3;
    }
#pragma unroll
    for (int o = 32; o; o >>= 1) ss += __shfl_xor(ss, o);
    float rs = rsqrtf(ss * (1.f / 768.f) + 1e-5f);
#pragma unroll
    for (int i = 0; i < 3; ++i) {
      int c4 = lane + 64 * i;
      float4 gv = ((const float4*)g)[c4];
      float4 bv = ((const float4*)b)[c4];
      float o0 = (v[i].x - mean) * rs * gv.x + bv.x;
      float o1 = (v[i].y - mean) * rs * gv.y + bv.y;
      float o2 = (v[i].z - mean) * rs * gv.z + bv.z;
      float o3 = (v[i].w - mean) * rs * gv.w + bv.w;
      ((unsigned*)(xx8 + (size_t)row * DIM))[c4] = pk_fp8x4(o0, o1, o2, o3);
      if (row < NB) {
        float4 fo; fo.x = o0; fo.y = o1; fo.z = o2; fo.w = o3;
        ((float4*)(q0f + (size_t)row * DIM))[c4] = fo;
      }
    }
  } else {
    int idx = blk - ROWS_ALL / 4;          // [0, 2880)
    int w = idx / 576;                     // matrix id, uniform per block
    int j4 = (idx % 576) * 256 + tid;      // float4 index within matrix
    const float* s = (w == 0) ? Wq : (w == 1) ? Wk : (w == 2) ? Wv
                   : (w == 3) ? fcw : pw;
    float4 v = ((const float4*)s)[j4];
    if (w < 3) {
      ((unsigned*)(w8 + (size_t)w * (DIM * DIM)))[j4] = pk_fp8x4(v.x, v.y, v.z, v.w);
    } else {
      ushort4 u; u.x = f2bf(v.x); u.y = f2bf(v.y); u.z = f2bf(v.z); u.w = f2bf(v.w);
      ((ushort4*)(wbf + (size_t)(w - 3) * (DIM * DIM)))[j4] = u;
    }
  }
}

// ======= fused QKV projection GEMMs: 128x128 tile, FP8, BK=128 ==========
// 6 K-steps (was 12): per-step drains/barriers halve again — the proven
// lever (24->12 was -30us). 128B rows with the row&7 8-block XOR = the
// measured zero-conflict bf16 pattern; fragments read as two kk-halves
// (one half's frags live at a time, keeping VGPR ~120). LDS 32KB single
// buffer -> 4 blocks/CU by LDS. Outputs bf16 (Q pre-scaled by log2e/8).
__global__ __launch_bounds__(256) void gemm_fused(
    const unsigned char* __restrict__ xxkv, const unsigned char* __restrict__ Wk8,
    unsigned short* __restrict__ Kbf,
    const unsigned char* __restrict__ Wv8, unsigned short* __restrict__ Vtb,
    const unsigned char* __restrict__ xxall, const unsigned char* __restrict__ Wq8,
    unsigned short* __restrict__ Qbf)
{
  __shared__ unsigned char Asm[128 * 128];   // 16KB
  __shared__ unsigned char Bsm[128 * 128];   // 16KB
  int tid = threadIdx.x, wid = tid >> 6, lane = tid & 63;
  int l15 = lane & 15, l4 = lane >> 4;

  int nwg = gridDim.x;
  int bid = blockIdx.x;
  int q8 = nwg >> 3, r8 = nwg & 7;
  int xcd = bid & 7, rank = bid >> 3;
  int swz = (xcd < r8 ? xcd * (q8 + 1) : r8 * (q8 + 1) + (xcd - r8) * q8) + rank;

  const unsigned char *A, *Bt;
  unsigned short* C;
  int N, row0, col0;
  const int K = DIM;                 // 768 fp8 bytes per row
  if (swz < 1176) {                  // K = xx_kv @ Wk^T
    A = xxkv; Bt = Wk8; C = Kbf; N = DIM;
    row0 = (swz / 6) * 128; col0 = (swz % 6) * 128;
  } else if (swz < 2352) {           // V^T = Wv @ xx_kv^T
    int inner = swz - 1176;
    A = Wv8; Bt = xxkv; C = Vtb; N = ROWS_KV;
    row0 = (inner % 6) * 128; col0 = (inner / 6) * 128;
  } else {                           // Q = xx_cls @ Wq^T (pre-scaled)
    int inner = swz - 2352;
    A = xxall; Bt = Wq8; C = Qbf; N = DIM;
    row0 = 0; col0 = inner * 128;
  }
  float csc = (swz >= 2352) ? 0.18033688011112042f : 1.0f;  // log2e/8 for Q

  // staging: thread t -> row (t>>3) within a 32-row pass, col-block
  // (t&7) ^ (row&7) pre-swizzled at the source; LDS stays linear.
  int srow = tid >> 3;               // 0..31
  int sb = (tid & 7) ^ (srow & 7);
  const unsigned char* Ag = A + (size_t)(row0 + srow) * K + sb * 16;
  const unsigned char* Bg = Bt + (size_t)(col0 + srow) * K + sb * 16;
  size_t rstep32 = (size_t)32 * K;

  f32x4 acc[4][4] = {};
  int wr = (wid >> 1) * 64, wc = (wid & 1) * 64;
  const int nk = K >> 7;             // 6 K-steps of BK=128 (128 bytes/row)
  for (int t = 0; t < nk; ++t) {
    {
      const unsigned char* a0 = Ag + (size_t)t * 128;
      const unsigned char* b0 = Bg + (size_t)t * 128;
      char* la = (char*)Asm + wid * 1024;
      char* lb = (char*)Bsm + wid * 1024;
#pragma unroll
      for (int i = 0; i < 4; ++i) {
        gload16(a0 + i * rstep32, la + i * 4096);
        gload16(b0 + i * rstep32, lb + i * 4096);
      }
    }
    asm volatile("s_waitcnt vmcnt(0)" ::: "memory");
    __builtin_amdgcn_s_barrier();
    asm volatile("" ::: "memory");
#pragma unroll
    for (int h = 0; h < 2; ++h) {    // kk-half: k-bytes [64h, 64h+64)
      i64x2 aF[4], bF[4];
#pragma unroll
      for (int m = 0; m < 4; ++m) {
        int row = wr + m * 16 + l15;
        aF[m] = *(const i64x2*)((const char*)Asm + row * 128 +
                                ((((h << 2) | l4) ^ (row & 7)) << 4));
      }
#pragma unroll
      for (int n = 0; n < 4; ++n) {
        int row = wc + n * 16 + l15;
        bF[n] = *(const i64x2*)((const char*)Bsm + row * 128 +
                                ((((h << 2) | l4) ^ (row & 7)) << 4));
      }
      __builtin_amdgcn_s_setprio(1);
#pragma unroll
      for (int j = 0; j < 2; ++j)
#pragma unroll
        for (int m = 0; m < 4; ++m)
#pragma unroll
          for (int n = 0; n < 4; ++n)
            acc[m][n] = __builtin_amdgcn_mfma_f32_16x16x32_fp8_fp8(
                aF[m][j], bF[n][j], acc[m][n], 0, 0, 0);
      __builtin_amdgcn_s_setprio(0);
    }
    asm volatile("" ::: "memory");
    __builtin_amdgcn_s_barrier();
    asm volatile("" ::: "memory");
  }
#pragma unroll
  for (int m = 0; m < 4; ++m)
#pragma unroll
    for (int n = 0; n < 4; ++n)
#pragma unroll
      for (int r = 0; r < 4; ++r) {
        int rr = row0 + wr + m * 16 + l4 * 4 + r;
        int cc = col0 + wc + n * 16 + l15;
        C[(size_t)rr * N + cc] = f2bf(acc[m][n][r] * csc);
      }
}

// ======= 128x128 tile GEMM (small M epilogue cases), BK=64, 1 barrier ===
// EPI 1: +bias, silu(1.702), bf16 store; 2: +bias +addsrc, f32 store
template <int EPI>
__global__ __launch_bounds__(256, 2) void gemm_bt64(
    const unsigned short* __restrict__ A, const unsigned short* __restrict__ Bt,
    void* __restrict__ Cout, int M, int N, int K,
    const float* __restrict__ bias, const float* __restrict__ addsrc)
{
  __shared__ unsigned short Asm[2][128 * 64];
  __shared__ unsigned short Bsm[2][128 * 64];
  int tid = threadIdx.x, wid = tid >> 6, lane = tid & 63;
  int l15 = lane & 15, l4 = lane >> 4;
  int row0 = blockIdx.y * 128, col0 = blockIdx.x * 128;

  int srow = tid >> 3;
  int scol = ((tid & 7) ^ (srow & 7)) << 4;
  const char* Ag = (const char*)A + (size_t)(row0 + srow) * K * 2 + scol;
  const char* Bg = (const char*)Bt + (size_t)(col0 + srow) * K * 2 + scol;
  size_t rstep32 = (size_t)32 * K * 2;

#define STAGE(buf, kt) do {                                           \
    const char* a0 = Ag + (size_t)(kt) * 128;                         \
    const char* b0 = Bg + (size_t)(kt) * 128;                         \
    char* la = (char*)Asm[buf] + wid * 1024;                          \
    char* lb = (char*)Bsm[buf] + wid * 1024;                          \
    gload16(a0,                la);                                   \
    gload16(a0 + rstep32,      la + 4096);                            \
    gload16(a0 + 2 * rstep32,  la + 8192);                            \
    gload16(a0 + 3 * rstep32,  la + 12288);                           \
    gload16(b0,                lb);                                   \
    gload16(b0 + rstep32,      lb + 4096);                            \
    gload16(b0 + 2 * rstep32,  lb + 8192);                            \
    gload16(b0 + 3 * rstep32,  lb + 12288);                           \
  } while (0)

  f32x4 acc[4][4] = {};
  int wr = (wid >> 1) * 64, wc = (wid & 1) * 64;
  int nk = K >> 6;                 // BK=64
  STAGE(0, 0);
  for (int t = 0; t < nk; ++t) {
    int cur = t & 1;
    __builtin_amdgcn_s_barrier();
    asm volatile("" ::: "memory");
    if (t + 1 < nk) {
      STAGE(cur ^ 1, t + 1);
      asm volatile("s_waitcnt vmcnt(8)" ::: "memory");
    } else {
      asm volatile("s_waitcnt vmcnt(0)" ::: "memory");
    }
    const char* Ab = (const char*)Asm[cur];
    const char* Bb = (const char*)Bsm[cur];
#pragma unroll
    for (int kk = 0; kk < 2; ++kk) {
      short8 aF[4], bF[4];
#pragma unroll
      for (int m = 0; m < 4; ++m) {
        int row = wr + m * 16 + l15;
        aF[m] = *(const short8*)(Ab + row * 128 + ((((kk << 2) | l4) ^ (row & 7)) << 4));
      }
#pragma unroll
      for (int n = 0; n < 4; ++n) {
        int row = wc + n * 16 + l15;
        bF[n] = *(const short8*)(Bb + row * 128 + ((((kk << 2) | l4) ^ (row & 7)) << 4));
      }
#pragma unroll
      for (int m = 0; m < 4; ++m)
#pragma unroll
        for (int n = 0; n < 4; ++n)
          acc[m][n] = __builtin_amdgcn_mfma_f32_16x16x32_bf16(aF[m], bF[n], acc[m][n], 0, 0, 0);
    }
    asm volatile("" ::: "memory");
  }
#undef STAGE
#pragma unroll
  for (int m = 0; m < 4; ++m)
#pragma unroll
    for (int n = 0; n < 4; ++n)
#pragma unroll
      for (int r = 0; r < 4; ++r) {
        int rr = row0 + wr + m * 16 + l4 * 4 + r;
        int cc = col0 + wc + n * 16 + l15;
        float v = acc[m][n][r];
        if (EPI == 1) {
          v += bias[cc];
          v = v / (1.f + __expf(-1.702f * v));
          ((unsigned short*)Cout)[(size_t)rr * N + cc] = f2bf(v);
        } else {
          v += bias[cc] + addsrc[(size_t)rr * N + cc];
          ((float*)Cout)[(size_t)rr * N + cc] = v;
        }
      }
}

// ---------------- flash-decode attention partials (swapped QK^T) --------
// Static-max softmax; Q pre-scaled by log2e/8 in gemm_fused, so
// p = exp2(S_scaled) directly — no per-score multiply.
__global__ __launch_bounds__(256, 4) void attn_partial(
    const unsigned short* __restrict__ Qb, const unsigned short* __restrict__ Kb,
    const unsigned short* __restrict__ Vt,
    unsigned short* __restrict__ Op, float* __restrict__ lp)
{
  __shared__ unsigned short Klds[2][64 * 64];
  __shared__ unsigned short Vlds[2][64 * 64];
  int tid = threadIdx.x, wid = tid >> 6, lane = tid & 63;
  int l15 = lane & 15, l4 = lane >> 4;
  int head = blockIdx.x >> 6, chunk = blockIdx.x & 63;
  int t0 = (49 * chunk) >> 3;
  int nkt = ((49 * (chunk + 1)) >> 3) - t0;   // 6 or 7

  short8 bQ[2][2];
#pragma unroll
  for (int m = 0; m < 2; ++m)
#pragma unroll
    for (int kk = 0; kk < 2; ++kk) {
      int qrow = wid * 32 + m * 16 + l15;
      bQ[m][kk] = *(const short8*)(Qb + (size_t)qrow * DIM + head * HD + kk * 32 + l4 * 8);
    }
  f32x4 accO[2][4] = {};
  float lrun[2] = { 0.f, 0.f };

  int srow = tid >> 3;                       // 0..31 within a 32-row pass
  int sblk = (tid & 7) ^ (srow & 7);
  const char* Kg = (const char*)(Kb + (size_t)(t0 * 64 + srow) * DIM + head * HD) + sblk * 16;
  const char* Vg = (const char*)(Vt + (size_t)(head * HD + srow) * ROWS_KV + t0 * 64) + sblk * 16;

#define STAGEKV(buf, kt) do {                                         \
    const char* k0 = Kg + (size_t)(kt) * 64 * DIM * 2;                \
    const char* v0 = Vg + (size_t)(kt) * 128;                         \
    char* lk = (char*)Klds[buf] + wid * 1024;                         \
    char* lv = (char*)Vlds[buf] + wid * 1024;                         \
    gload16(k0,                        lk);                           \
    gload16(k0 + (size_t)32 * DIM * 2, lk + 4096);                    \
    gload16(v0,                        lv);                           \
    gload16(v0 + (size_t)32 * ROWS_KV * 2, lv + 4096);                \
  } while (0)

  STAGEKV(0, 0);
  for (int kt = 0; kt < nkt; ++kt) {
    int cur = kt & 1;
    __builtin_amdgcn_s_barrier();   // all waves done reading buf[cur^1]
    asm volatile("" ::: "memory");
    if (kt + 1 < nkt) {
      STAGEKV(cur ^ 1, kt + 1);
      asm volatile("s_waitcnt vmcnt(4)" ::: "memory");
    } else {
      asm volatile("s_waitcnt vmcnt(0)" ::: "memory");
    }

    // S^T[key][q]: sc[n][m][r] = Ssc[q0+m*16+l15][key = n*16 + l4*4 + r]
    f32x4 sc[4][2] = {};
    __builtin_amdgcn_s_setprio(1);
#pragma unroll
    for (int kk = 0; kk < 2; ++kk) {
      short8 aK[4];
#pragma unroll
      for (int n = 0; n < 4; ++n) {
        int krow = n * 16 + l15;
        int blk = ((kk << 2) | l4) ^ (krow & 7);
        aK[n] = *(const short8*)((const char*)Klds[cur] + krow * 128 + blk * 16);
      }
#pragma unroll
      for (int n = 0; n < 4; ++n)
#pragma unroll
        for (int m = 0; m < 2; ++m)
          sc[n][m] = __builtin_amdgcn_mfma_f32_16x16x32_bf16(aK[n], bQ[m][kk], sc[n][m], 0, 0, 0);
    }
    __builtin_amdgcn_s_setprio(0);

    // static-max softmax: p = 2^(S_scaled); sum; pack bf16 via cvt_pk
    short8 pB[2][2];
#pragma unroll
    for (int m = 0; m < 2; ++m) {
      float rsum = 0.f;
#pragma unroll
      for (int n = 0; n < 4; ++n)
#pragma unroll
        for (int r = 0; r < 4; ++r) {
          float p;
          asm("v_exp_f32 %0, %1" : "=v"(p) : "v"(sc[n][m][r]));
          sc[n][m][r] = p;
          rsum += p;
        }
      rsum += __shfl_xor(rsum, 16);
      rsum += __shfl_xor(rsum, 32);
      lrun[m] += rsum;
#pragma unroll
      for (int kk2 = 0; kk2 < 2; ++kk2) {
        uint4v pw;
#pragma unroll
        for (int w = 0; w < 4; ++w) {
          int n = 2 * kk2 + (w >> 1);
          int r0 = (w & 1) * 2;
          unsigned int u;
          asm("v_cvt_pk_bf16_f32 %0, %1, %2"
              : "=v"(u) : "v"(sc[n][m][r0]), "v"(sc[n][m][r0 + 1]));
          pw[w] = u;
        }
        pB[m][kk2] = __builtin_bit_cast(short8, pw);
      }
    }

    // O^T += V'^T P'
    __builtin_amdgcn_s_setprio(1);
#pragma unroll
    for (int kk2 = 0; kk2 < 2; ++kk2) {
      short8 aV[4];
#pragma unroll
      for (int nb = 0; nb < 4; ++nb) {
        int row = nb * 16 + l15;
        int blk1 = (kk2 << 2) | (l4 >> 1);
        int in1 = (l4 & 1) << 3;
        const char* vb = (const char*)Vlds[cur] + row * 128;
        short4v lo = *(const short4v*)(vb + (((blk1 ^ (row & 7)) << 4) | in1));
        short4v hi = *(const short4v*)(vb + ((((blk1 + 2) ^ (row & 7)) << 4) | in1));
        aV[nb] = __builtin_shufflevector(lo, hi, 0, 1, 2, 3, 4, 5, 6, 7);
      }
#pragma unroll
      for (int m = 0; m < 2; ++m)
#pragma unroll
        for (int nb = 0; nb < 4; ++nb)
          accO[m][nb] = __builtin_amdgcn_mfma_f32_16x16x32_bf16(aV[nb], pB[m][kk2], accO[m][nb], 0, 0, 0);
    }
    __builtin_amdgcn_s_setprio(0);
    asm volatile("" ::: "memory");
  }
#undef STAGEKV
  size_t pb = (size_t)(head * NCHUNK + chunk) * 128;
#pragma unroll
  for (int m = 0; m < 2; ++m) {
    int q = wid * 32 + m * 16 + l15;
#pragma unroll
    for (int nb = 0; nb < 4; ++nb) {
      ushort4 o;
      o.x = f2bf(accO[m][nb][0]); o.y = f2bf(accO[m][nb][1]);
      o.z = f2bf(accO[m][nb][2]); o.w = f2bf(accO[m][nb][3]);
      *(ushort4*)(Op + (pb + q) * 64 + nb * 16 + l4 * 4) = o;
    }
    if (l4 == 0) {
      lp[pb + q] = lrun[m];
    }
  }
}

// ------- combine partials (plain sums; static max) + q1 + LN2 -> h -----
__device__ __forceinline__ float blk_sum256(float v, volatile float* red) {
  int tid = threadIdx.x;
#pragma unroll
  for (int o = 32; o; o >>= 1) v += __shfl_xor(v, o);
  __syncthreads();
  if ((tid & 63) == 0) red[tid >> 6] = v;
  __syncthreads();
  return red[0] + red[1] + red[2] + red[3];
}

__global__ __launch_bounds__(256) void combine_ln2(
    const unsigned short* __restrict__ Op, const float* __restrict__ lp,
    const float* __restrict__ q0f, const float* __restrict__ g2, const float* __restrict__ b2,
    float* __restrict__ q1, unsigned short* __restrict__ hb)
{
  int q = blockIdx.x, tid = threadIdx.x;
  __shared__ float lS[HEADS * NCHUNK];
  __shared__ float red[4];
  for (int i = tid; i < HEADS * NCHUNK; i += 256)
    lS[i] = lp[(size_t)i * 128 + q];
  __syncthreads();
  float vals[3];
#pragma unroll
  for (int ii = 0; ii < 3; ++ii) {
    int c = tid + ii * 256;
    int h = c >> 6, d = c & 63;
    float num = 0.f, den = 0.f;
    for (int cc = 0; cc < NCHUNK; ++cc) {
      den += lS[h * NCHUNK + cc];
      num += bf2f(Op[((size_t)(h * NCHUNK + cc) * 128 + q) * 64 + d]);
    }
    float ctx = 0.5f * num / den;
    float v = q0f[(size_t)q * DIM + c] + ctx;
    q1[(size_t)q * DIM + c] = v;
    vals[ii] = v;
  }
  float s = blk_sum256(vals[0] + vals[1] + vals[2], red);
  float mean = s * (1.f / 768.f);
  float d0 = vals[0] - mean, d1 = vals[1] - mean, d2 = vals[2] - mean;
  float ss = blk_sum256(d0 * d0 + d1 * d1 + d2 * d2, red);
  float rs = rsqrtf(ss * (1.f / 768.f) + 1e-5f);
#pragma unroll
  for (int ii = 0; ii < 3; ++ii) {
    int c = tid + ii * 256;
    hb[(size_t)q * DIM + c] = f2bf((vals[ii] - mean) * rs * g2[c] + b2[c]);
  }
}

// ------------------------------- host -----------------------------------
extern "C" void kernel_launch(void* const* d_in, const int* in_sizes, int n_in,
                              void* d_out, int out_size, void* d_ws, size_t ws_size,
                              hipStream_t stream) {
  const float* x   = (const float*)d_in[0];
  const float* cls = (const float*)d_in[1];
  const float* g1  = (const float*)d_in[2];
  const float* b1  = (const float*)d_in[3];
  const float* g2  = (const float*)d_in[4];
  const float* b2  = (const float*)d_in[5];
  const float* Wq  = (const float*)d_in[6];
  const float* Wk  = (const float*)d_in[7];
  const float* Wv  = (const float*)d_in[8];
  const float* fcw = (const float*)d_in[13];
  const float* fcb = (const float*)d_in[14];
  const float* pw  = (const float*)d_in[15];
  const float* pb  = (const float*)d_in[16];

  char* ws = (char*)d_ws;
  size_t off = 0;
  auto alloc = [&](size_t bytes) {
    char* p = ws + off;
    off += (bytes + 255) & ~(size_t)255;
    return p;
  };
  unsigned char*  xx8  = (unsigned char*)alloc((size_t)ROWS_ALL * DIM);
  float*          q0f  = (float*)alloc((size_t)NB * DIM * 4);
  unsigned short* Kbf  = (unsigned short*)alloc((size_t)ROWS_KV * DIM * 2);
  unsigned short* Vtb  = (unsigned short*)alloc((size_t)DIM * ROWS_KV * 2);
  unsigned short* Qbf  = (unsigned short*)alloc((size_t)NB * DIM * 2);
  unsigned char*  w8   = (unsigned char*)alloc((size_t)3 * DIM * DIM);
  unsigned short* wbf  = (unsigned short*)alloc((size_t)2 * DIM * DIM * 2);
  unsigned short* Opar = (unsigned short*)alloc((size_t)HEADS * NCHUNK * 128 * 64 * 2);
  float*          lpar = (float*)alloc((size_t)HEADS * NCHUNK * 128 * 4);
  float*          q1   = (float*)alloc((size_t)NB * DIM * 4);
  unsigned short* hb   = (unsigned short*)alloc((size_t)NB * DIM * 2);
  unsigned short* m1b  = (unsigned short*)alloc((size_t)NB * DIM * 2);

  unsigned char* Wq8 = w8;
  unsigned char* Wk8 = w8 + (size_t)1 * DIM * DIM;
  unsigned char* Wv8 = w8 + (size_t)2 * DIM * DIM;
  unsigned short* fwb = wbf;
  unsigned short* pwb = wbf + (size_t)1 * DIM * DIM;

  // fused LN1 + weight casts (6304 LN blocks + 2880 cast blocks)
  ln1_cast<<<ROWS_ALL / 4 + 2880, 256, 0, stream>>>(
      x, cls, g1, b1, xx8, q0f, Wq, Wk, Wv, fcw, pw, w8, wbf);

  // fused K / V^T / Q projections (2358 blocks, fp8 inputs, BK=128)
  gemm_fused<<<1176 + 1176 + 6, 256, 0, stream>>>(
      xx8 + (size_t)NB * DIM, Wk8, Kbf, Wv8, Vtb, xx8, Wq8, Qbf);

  attn_partial<<<HEADS * NCHUNK, 256, 0, stream>>>(Qbf, Kbf, Vtb, Opar, lpar);
  combine_ln2<<<NB, 256, 0, stream>>>(Opar, lpar, q0f, g2, b2, q1, hb);

  // m1 = silu(h @ fc_w^T + fc_b)
  gemm_bt64<1><<<dim3(DIM / 128, 1), 256, 0, stream>>>(
      hb, fwb, m1b, NB, DIM, DIM, fcb, nullptr);
  // out = q1 + m1 @ proj_w^T + proj_b
  gemm_bt64<2><<<dim3(DIM / 128, 1), 256, 0, stream>>>(
      m1b, pwb, d_out, NB, DIM, DIM, pb, q1);
}